// Round 3
// baseline (3683.281 us; speedup 1.0000x reference)
//
#include <hip/hip_runtime.h>
#include <hip/hip_cooperative_groups.h>

namespace cg = cooperative_groups;

typedef unsigned short u16;
typedef unsigned int u32;
typedef __attribute__((ext_vector_type(8))) __bf16 bf16x8;
typedef __attribute__((ext_vector_type(4))) float f32x4;

#define DEVI static __device__ __forceinline__

#define BB 32
#define SS 64
#define TT 63
#define VV 32000
#define EE 300
#define EP 320
#define HH 1024
#define H3 3072
#define MM 2016
#define MP 2048

DEVI u16 f2bf(float f) {
  u32 x = __float_as_uint(f);
  u32 r = x + 0x7FFFu + ((x >> 16) & 1u);
  return (u16)(r >> 16);
}
DEVI float bf2f(u16 h) { return __uint_as_float(((u32)h) << 16); }
DEVI void split2(float x, u16& hi, u16& lo) {
  hi = f2bf(x);
  lo = f2bf(x - bf2f(hi));
}
DEVI float sigm(float x) { return 1.0f / (1.0f + __expf(-x)); }
DEVI float tanh_(float x) { return 2.0f / (1.0f + __expf(-2.0f * x)) - 1.0f; }

DEVI void gl_lds16(const u16* g, u16* l) {
  __builtin_amdgcn_global_load_lds((const __attribute__((address_space(1))) void*)g,
                                   (__attribute__((address_space(3))) void*)l,
                                   16, 0, 0);
}

DEVI f32x4 mfma_bf16(bf16x8 a, bf16x8 b, f32x4 c) {
  return __builtin_amdgcn_mfma_f32_16x16x32_bf16(a, b, c, 0, 0, 0);
}

// ---------------- converts / gather ----------------

__global__ void cvt_bf16(const float* __restrict__ in, u16* __restrict__ out, int n4) {
  int i = blockIdx.x * 256 + threadIdx.x;
  int stride = gridDim.x * 256;
  for (; i < n4; i += stride) {
    float4 v = ((const float4*)in)[i];
    ushort4 o;
    o.x = f2bf(v.x); o.y = f2bf(v.y); o.z = f2bf(v.z); o.w = f2bf(v.w);
    ((ushort4*)out)[i] = o;
  }
}

__global__ void cvt_split(const float* __restrict__ in, u16* __restrict__ hi,
                          u16* __restrict__ lo, int n4) {
  int i = blockIdx.x * 256 + threadIdx.x;
  int stride = gridDim.x * 256;
  for (; i < n4; i += stride) {
    float4 v = ((const float4*)in)[i];
    ushort4 h, l;
    split2(v.x, h.x, l.x);
    split2(v.y, h.y, l.y);
    split2(v.z, h.z, l.z);
    split2(v.w, h.w, l.w);
    ((ushort4*)hi)[i] = h;
    ((ushort4*)lo)[i] = l;
  }
}

__global__ void cvt_wi0_split(const float* __restrict__ W, u16* __restrict__ hi,
                              u16* __restrict__ lo) {
  int i = blockIdx.x * 256 + threadIdx.x;
  int stride = gridDim.x * 256;
  for (; i < H3 * EP; i += stride) {
    int r = i / EP, c = i % EP;
    u16 h = 0, l = 0;
    if (c < EE) split2(W[(size_t)r * EE + c], h, l);
    hi[i] = h;
    lo[i] = l;
  }
}

__global__ void gather_x_split(const int* __restrict__ sent, const float* __restrict__ emb,
                               u16* __restrict__ xh, u16* __restrict__ xl) {
  int i = blockIdx.x * 256 + threadIdx.x;
  int stride = gridDim.x * 256;
  for (; i < MM * EP; i += stride) {
    int m = i / EP, c = i % EP;
    int t = m >> 5, b = m & 31;
    int tok = sent[b * SS + t];
    u16 h = 0, l = 0;
    if (c < EE) split2(emb[(size_t)tok * EE + c], h, l);
    xh[i] = h;
    xl[i] = l;
  }
}

// ---------------- GEMM: C[m][n] = A[m][:] . B[n][:] + bias[n] ----------------
// A [MP][lda] bf16, B [N][lda] bf16 (both K-contiguous), 128x128 tile, BK=64.
// SPLIT: hi/lo planes for both operands, 3 MFMA products (fp32-accurate).

template <bool REMAP, bool SPLIT>
__global__ __launch_bounds__(256) void gemm_bt(const u16* __restrict__ Ah,
                                               const u16* __restrict__ Al, int lda,
                                               const u16* __restrict__ Bh,
                                               const u16* __restrict__ Bl,
                                               const float* __restrict__ bias,
                                               float* __restrict__ out, int out_stride,
                                               int Ksteps, int Mtiles, int Mvalid) {
  __shared__ u16 As[(SPLIT ? 2 : 1) * 128 * 64];
  __shared__ u16 Bs[(SPLIT ? 2 : 1) * 128 * 64];
  const int bid = blockIdx.x;
  const int mtile = bid % Mtiles, ntile = bid / Mtiles;
  const int tid = threadIdx.x;
  const int lane = tid & 63, wave = tid >> 6;
  const int wrow = (wave & 1) * 64, wcol = (wave >> 1) * 64;
  const int l15 = lane & 15, kg = lane >> 4;

  f32x4 acc[4][4];
#pragma unroll
  for (int i = 0; i < 4; ++i)
#pragma unroll
    for (int j = 0; j < 4; ++j) {
      f32x4 z = {0.f, 0.f, 0.f, 0.f};
      acc[i][j] = z;
    }

  for (int ks = 0; ks < Ksteps; ++ks) {
    int k0 = ks * 64;
#pragma unroll
    for (int it = 0; it < 4; ++it) {
      int c = it * 256 + tid;
      int r = c >> 3, kc = (c & 7) * 8;
      gl_lds16(Ah + (size_t)(mtile * 128 + r) * lda + k0 + kc, &As[c * 8]);
      gl_lds16(Bh + (size_t)(ntile * 128 + r) * lda + k0 + kc, &Bs[c * 8]);
      if constexpr (SPLIT) {
        gl_lds16(Al + (size_t)(mtile * 128 + r) * lda + k0 + kc, &As[8192 + c * 8]);
        gl_lds16(Bl + (size_t)(ntile * 128 + r) * lda + k0 + kc, &Bs[8192 + c * 8]);
      }
    }
    __syncthreads();
#pragma unroll
    for (int kk = 0; kk < 2; ++kk) {
      bf16x8 ah[4], bh[4], al[4], bl[4];
#pragma unroll
      for (int i = 0; i < 4; ++i) {
        int ao = (wrow + i * 16 + l15) * 64 + kk * 32 + kg * 8;
        int bo = (wcol + i * 16 + l15) * 64 + kk * 32 + kg * 8;
        ah[i] = *(const bf16x8*)&As[ao];
        bh[i] = *(const bf16x8*)&Bs[bo];
        if constexpr (SPLIT) {
          al[i] = *(const bf16x8*)&As[8192 + ao];
          bl[i] = *(const bf16x8*)&Bs[8192 + bo];
        }
      }
#pragma unroll
      for (int i = 0; i < 4; ++i)
#pragma unroll
        for (int j = 0; j < 4; ++j) {
          f32x4 t = mfma_bf16(ah[i], bh[j], acc[i][j]);
          if constexpr (SPLIT) {
            t = mfma_bf16(ah[i], bl[j], t);
            t = mfma_bf16(al[i], bh[j], t);
          }
          acc[i][j] = t;
        }
    }
    __syncthreads();
  }

  const int r0 = kg * 4;
#pragma unroll
  for (int i = 0; i < 4; ++i) {
    int mbase = mtile * 128 + wrow + i * 16 + r0;
#pragma unroll
    for (int j = 0; j < 4; ++j) {
      int n = ntile * 128 + wcol + j * 16 + l15;
      float bv = bias[n];
#pragma unroll
      for (int reg = 0; reg < 4; ++reg) {
        int m = mbase + reg;
        if (m < Mvalid) {
          float v = acc[i][j][reg] + bv;
          size_t oidx;
          if (REMAP) {
            int b = m & 31, s = m >> 5;
            oidx = ((size_t)(b * TT + s)) * VV + n;
          } else {
            oidx = (size_t)m * out_stride + n;
          }
          out[oidx] = v;
        }
      }
    }
  }
}

// ---------------- recurrence (cooperative, 96 WGs, 64 phases) ----------------

struct RecArgs {
  const u16 *wh0h, *wh0l, *wi1h, *wi1l, *wh1h, *wh1l;
  const float *gx0, *bh0, *bi1, *bh1;
  u16 *h0h, *h0l, *h1h, *h1l, *hs;
};

__global__ __launch_bounds__(256, 1) void rec_kernel(RecArgs ra) {
  cg::grid_group grid = cg::this_grid();
  __shared__ float gh[96 * 33];
  const int tid = threadIdx.x;
  const int lane = tid & 63, wave = tid >> 6;
  const int wg = blockIdx.x;
  const bool isL0 = wg < 32;
  const int Jbase = isL0 ? (wg * 32) : ((wg - 32) * 16);
  const int l15 = lane & 15;
  const int kg = lane >> 4;
  const int klo = kg * 8;

  for (int p = 0; p < 64; ++p) {
    const int pb = p & 1, qb = (p + 1) & 1;
    if (isL0) {
      if (p < TT) {
        const int rt = wave >> 1, ct0 = (wave & 1) * 3;
        size_t aoff = (size_t)qb * (BB * HH) + (size_t)(rt * 16 + l15) * HH + klo;
        const u16* ah = ra.h0h + aoff;
        const u16* al = ra.h0l + aoff;
        const u16 *bh[3], *bl[3];
#pragma unroll
        for (int t = 0; t < 3; ++t) {
          int ct = ct0 + t;
          size_t brow = (size_t)((ct >> 1) * HH + Jbase + (ct & 1) * 16 + l15);
          bh[t] = ra.wh0h + brow * HH + klo;
          bl[t] = ra.wh0l + brow * HH + klo;
        }
        f32x4 z = {0.f, 0.f, 0.f, 0.f};
        f32x4 acc[3] = {z, z, z};
#pragma unroll 4
        for (int kk = 0; kk < 32; ++kk) {
          bf16x8 Ah = *(const bf16x8*)(ah + kk * 32);
          bf16x8 Al = *(const bf16x8*)(al + kk * 32);
#pragma unroll
          for (int t = 0; t < 3; ++t) {
            bf16x8 Bh = *(const bf16x8*)(bh[t] + kk * 32);
            bf16x8 Bl = *(const bf16x8*)(bl[t] + kk * 32);
            acc[t] = mfma_bf16(Ah, Bh, acc[t]);
            acc[t] = mfma_bf16(Ah, Bl, acc[t]);
            acc[t] = mfma_bf16(Al, Bh, acc[t]);
          }
        }
#pragma unroll
        for (int t = 0; t < 3; ++t) {
          int cl = (ct0 + t) * 16 + l15;
#pragma unroll
          for (int r = 0; r < 4; ++r) gh[cl * 33 + rt * 16 + kg * 4 + r] = acc[t][r];
        }
      }
      __syncthreads();
      if (p < TT) {
        const u16* hhp = ra.h0h + qb * (BB * HH);
        const u16* hlp = ra.h0l + qb * (BB * HH);
        u16* hhc = ra.h0h + pb * (BB * HH);
        u16* hlc = ra.h0l + pb * (BB * HH);
        const float* gx = ra.gx0 + (size_t)p * (BB * H3);
#pragma unroll
        for (int q = 0; q < 4; ++q) {
          int e = q * 256 + tid;
          int j = e >> 5, b = e & 31;
          int gj = Jbase + j;
          float rh = gh[(j)*33 + b] + ra.bh0[gj];
          float zh = gh[(32 + j) * 33 + b] + ra.bh0[HH + gj];
          float nh = gh[(64 + j) * 33 + b] + ra.bh0[2 * HH + gj];
          const float* gxb = gx + (size_t)b * H3;
          float r = sigm(gxb[gj] + rh);
          float zz = sigm(gxb[HH + gj] + zh);
          float n = tanh_(gxb[2 * HH + gj] + r * nh);
          float hp = bf2f(hhp[b * HH + gj]) + bf2f(hlp[b * HH + gj]);
          float hn = (1.f - zz) * n + zz * hp;
          u16 hi, lo;
          split2(hn, hi, lo);
          hhc[b * HH + gj] = hi;
          hlc[b * HH + gj] = lo;
        }
      }
    } else {
      if (p >= 1) {
        const int rt = wave >> 1, src = wave & 1;
        size_t aoff = (size_t)qb * (BB * HH) + (size_t)(rt * 16 + l15) * HH + klo;
        const u16* ah = (src ? ra.h1h : ra.h0h) + aoff;
        const u16* al = (src ? ra.h1l : ra.h0l) + aoff;
        const u16* Bwh = src ? ra.wh1h : ra.wi1h;
        const u16* Bwl = src ? ra.wh1l : ra.wi1l;
        const u16 *bh[3], *bl[3];
#pragma unroll
        for (int g = 0; g < 3; ++g) {
          size_t brow = (size_t)(g * HH + Jbase + l15);
          bh[g] = Bwh + brow * HH + klo;
          bl[g] = Bwl + brow * HH + klo;
        }
        f32x4 z = {0.f, 0.f, 0.f, 0.f};
        f32x4 acc[3] = {z, z, z};
#pragma unroll 4
        for (int kk = 0; kk < 32; ++kk) {
          bf16x8 Ah = *(const bf16x8*)(ah + kk * 32);
          bf16x8 Al = *(const bf16x8*)(al + kk * 32);
#pragma unroll
          for (int g = 0; g < 3; ++g) {
            bf16x8 Bh = *(const bf16x8*)(bh[g] + kk * 32);
            bf16x8 Bl = *(const bf16x8*)(bl[g] + kk * 32);
            acc[g] = mfma_bf16(Ah, Bh, acc[g]);
            acc[g] = mfma_bf16(Ah, Bl, acc[g]);
            acc[g] = mfma_bf16(Al, Bh, acc[g]);
          }
        }
#pragma unroll
        for (int g = 0; g < 3; ++g) {
          int cl = (src * 3 + g) * 16 + l15;
#pragma unroll
          for (int r = 0; r < 4; ++r) gh[cl * 33 + rt * 16 + kg * 4 + r] = acc[g][r];
        }
      }
      __syncthreads();
      if (p >= 1) {
        const u16* hhp = ra.h1h + qb * (BB * HH);
        const u16* hlp = ra.h1l + qb * (BB * HH);
        u16* hhc = ra.h1h + pb * (BB * HH);
        u16* hlc = ra.h1l + pb * (BB * HH);
#pragma unroll
        for (int q = 0; q < 2; ++q) {
          int e = q * 256 + tid;
          int j = e >> 5, b = e & 31;
          int gj = Jbase + j;
          float gir = gh[(j)*33 + b] + ra.bi1[gj];
          float giz = gh[(16 + j) * 33 + b] + ra.bi1[HH + gj];
          float gin = gh[(32 + j) * 33 + b] + ra.bi1[2 * HH + gj];
          float ghr = gh[(48 + j) * 33 + b] + ra.bh1[gj];
          float ghz = gh[(64 + j) * 33 + b] + ra.bh1[HH + gj];
          float ghn = gh[(80 + j) * 33 + b] + ra.bh1[2 * HH + gj];
          float r = sigm(gir + ghr);
          float zz = sigm(giz + ghz);
          float n = tanh_(gin + r * ghn);
          float hp = bf2f(hhp[b * HH + gj]) + bf2f(hlp[b * HH + gj]);
          float hn = (1.f - zz) * n + zz * hp;
          u16 hi, lo;
          split2(hn, hi, lo);
          hhc[b * HH + gj] = hi;
          hlc[b * HH + gj] = lo;
          ra.hs[((size_t)(p - 1) * BB + b) * HH + gj] = hi;
        }
      }
    }
    grid.sync();
  }
}

// ---------------- row reductions + loss ----------------

__global__ __launch_bounds__(256) void rowred_kernel(const float* __restrict__ logits,
                                                     const int* __restrict__ sent,
                                                     const int* __restrict__ length,
                                                     float* __restrict__ tok) {
  __shared__ float red[8];
  const int row = blockIdx.x;  // b*63 + s
  const int b = row / TT, s = row % TT;
  const float* p = logits + (size_t)row * VV;
  const int tid = threadIdx.x;

  float m = -1e30f;
  for (int i = tid; i < VV; i += 256) m = fmaxf(m, p[i]);
  for (int off = 1; off < 64; off <<= 1) m = fmaxf(m, __shfl_xor(m, off));
  if ((tid & 63) == 0) red[tid >> 6] = m;
  __syncthreads();
  m = fmaxf(fmaxf(red[0], red[1]), fmaxf(red[2], red[3]));

  float sum = 0.f;
  for (int i = tid; i < VV; i += 256) sum += __expf(p[i] - m);
  for (int off = 1; off < 64; off <<= 1) sum += __shfl_xor(sum, off);
  if ((tid & 63) == 0) red[4 + (tid >> 6)] = sum;
  __syncthreads();
  if (tid == 0) {
    float tot = red[4] + red[5] + red[6] + red[7];
    float lse = m + __logf(tot);
    int tgt = sent[b * SS + s + 1];
    float tl = p[tgt] - lse;
    if (s >= length[b] - 1) tl = 0.f;
    tok[row] = tl;
  }
}

__global__ void loss_kernel(const float* __restrict__ tok, const int* __restrict__ length,
                            float* __restrict__ out0) {
  int lane = threadIdx.x;
  float v = 0.f;
  if (lane < BB) {
    float s = 0.f;
    for (int t = 0; t < TT; ++t) s += tok[lane * TT + t];
    float ln = (float)(length[lane] - 1);
    v = -s / ln;
  }
  v += __shfl_down(v, 16);
  v += __shfl_down(v, 8);
  v += __shfl_down(v, 4);
  v += __shfl_down(v, 2);
  v += __shfl_down(v, 1);
  if (lane == 0) out0[0] = v / (float)BB;
}

// ---------------- host ----------------

extern "C" void kernel_launch(void* const* d_in, const int* in_sizes, int n_in,
                              void* d_out, int out_size, void* d_ws, size_t ws_size,
                              hipStream_t stream) {
  const int* sent = (const int*)d_in[0];
  const int* length = (const int*)d_in[1];
  const float* emb = (const float*)d_in[2];
  const float* Wi0 = (const float*)d_in[3];
  const float* Wh0 = (const float*)d_in[4];
  const float* bi0 = (const float*)d_in[5];
  const float* bh0 = (const float*)d_in[6];
  const float* Wi1 = (const float*)d_in[7];
  const float* Wh1 = (const float*)d_in[8];
  const float* bi1 = (const float*)d_in[9];
  const float* bh1 = (const float*)d_in[10];
  const float* Wout = (const float*)d_in[11];
  const float* bout = (const float*)d_in[12];
  float* out = (float*)d_out;

  char* ws = (char*)d_ws;
  size_t off = 0;
  auto alloc = [&](size_t b) {
    char* p = ws + off;
    off = (off + b + 255) & ~(size_t)255;
    return p;
  };
  // Region A: recurrence-phase-only buffers; woutb is aliased over it after rec.
  char* regionA = ws;
  {
    size_t a = 0;
    auto allocA = [&](size_t b) {
      char* p = regionA + a;
      a = (a + b + 255) & ~(size_t)255;
      return p;
    };
    (void)allocA;
  }
  size_t offA = 0;
  auto allocA = [&](size_t b) {
    char* p = regionA + offA;
    offA = (offA + b + 255) & ~(size_t)255;
    return p;
  };
  u16* wh0h = (u16*)allocA((size_t)H3 * HH * 2);
  u16* wh0l = (u16*)allocA((size_t)H3 * HH * 2);
  u16* wi1h = (u16*)allocA((size_t)H3 * HH * 2);
  u16* wi1l = (u16*)allocA((size_t)H3 * HH * 2);
  u16* wh1h = (u16*)allocA((size_t)H3 * HH * 2);
  u16* wh1l = (u16*)allocA((size_t)H3 * HH * 2);
  u16* wi0h = (u16*)allocA((size_t)H3 * EP * 2);
  u16* wi0l = (u16*)allocA((size_t)H3 * EP * 2);
  u16* xh = (u16*)allocA((size_t)MP * EP * 2);
  u16* xl = (u16*)allocA((size_t)MP * EP * 2);
  float* gx0 = (float*)allocA((size_t)MM * H3 * 4);
  size_t regionA_size = offA;                        // ~69 MB
  u16* woutb = (u16*)regionA;                        // aliased, used after rec
  size_t wout_bytes = (size_t)VV * HH * 2;           // 65.5 MB <= regionA_size
  off = (regionA_size > wout_bytes ? regionA_size : wout_bytes);
  off = (off + 255) & ~(size_t)255;

  u16* hs = (u16*)alloc((size_t)MP * HH * 2);
  u16* h0h = (u16*)alloc((size_t)2 * BB * HH * 2);
  u16* h0l = (u16*)alloc((size_t)2 * BB * HH * 2);
  u16* h1h = (u16*)alloc((size_t)2 * BB * HH * 2);
  u16* h1l = (u16*)alloc((size_t)2 * BB * HH * 2);
  float* tok = (float*)alloc((size_t)MM * 4);

  hipMemsetAsync(h0h, 0, (size_t)2 * BB * HH * 2, stream);
  hipMemsetAsync(h0l, 0, (size_t)2 * BB * HH * 2, stream);
  hipMemsetAsync(h1h, 0, (size_t)2 * BB * HH * 2, stream);
  hipMemsetAsync(h1l, 0, (size_t)2 * BB * HH * 2, stream);
  hipMemsetAsync(hs, 0, (size_t)MP * HH * 2, stream);
  hipMemsetAsync(xh + (size_t)MM * EP, 0, (size_t)(MP - MM) * EP * 2, stream);
  hipMemsetAsync(xl + (size_t)MM * EP, 0, (size_t)(MP - MM) * EP * 2, stream);

  cvt_split<<<2048, 256, 0, stream>>>(Wh0, wh0h, wh0l, H3 * HH / 4);
  cvt_split<<<2048, 256, 0, stream>>>(Wi1, wi1h, wi1l, H3 * HH / 4);
  cvt_split<<<2048, 256, 0, stream>>>(Wh1, wh1h, wh1l, H3 * HH / 4);
  cvt_wi0_split<<<512, 256, 0, stream>>>(Wi0, wi0h, wi0l);
  gather_x_split<<<512, 256, 0, stream>>>(sent, emb, xh, xl);

  gemm_bt<false, true><<<16 * 24, 256, 0, stream>>>(xh, xl, EP, wi0h, wi0l, bi0, gx0, H3,
                                                    5, 16, MM);

  RecArgs ra{wh0h, wh0l, wi1h, wi1l, wh1h, wh1l, gx0, bh0, bi1, bh1,
             h0h,  h0l,  h1h,  h1l,  hs};
  void* kargs[] = {(void*)&ra};
  hipLaunchCooperativeKernel((void*)rec_kernel, dim3(96), dim3(256), kargs, 0, stream);

  // Wout conversion AFTER rec: woutb aliases the (now dead) recurrence weights.
  cvt_bf16<<<2048, 256, 0, stream>>>(Wout, woutb, VV * HH / 4);

  gemm_bt<true, false><<<16 * 250, 256, 0, stream>>>(hs, nullptr, HH, woutb, nullptr, bout,
                                                     out + 1, VV, 16, 16, MM);

  rowred_kernel<<<MM, 256, 0, stream>>>(out + 1, sent, length, tok);
  loss_kernel<<<1, 64, 0, stream>>>(tok, length, out);
}

// Round 5
// 2589.502 us; speedup vs baseline: 1.4224x; 1.4224x over previous
//
#include <hip/hip_runtime.h>
#include <hip/hip_cooperative_groups.h>

namespace cg = cooperative_groups;

typedef unsigned short u16;
typedef unsigned int u32;
typedef _Float16 f16;
typedef __attribute__((ext_vector_type(8))) __bf16 bf16x8;
typedef __attribute__((ext_vector_type(8))) _Float16 f16x8;
typedef __attribute__((ext_vector_type(4))) _Float16 f16x4;
typedef __attribute__((ext_vector_type(4))) float f32x4;

#define DEVI static __device__ __forceinline__

#define BB 32
#define SS 64
#define TT 63
#define VV 32000
#define EE 300
#define EP 320
#define HH 1024
#define H3 3072
#define MM 2016
#define MP 2048

DEVI u16 f2bf(float f) {
  u32 x = __float_as_uint(f);
  u32 r = x + 0x7FFFu + ((x >> 16) & 1u);
  return (u16)(r >> 16);
}
DEVI float bf2f(u16 h) { return __uint_as_float(((u32)h) << 16); }
DEVI void split2(float x, u16& hi, u16& lo) {
  hi = f2bf(x);
  lo = f2bf(x - bf2f(hi));
}
DEVI float sigm(float x) { return 1.0f / (1.0f + __expf(-x)); }
DEVI float tanh_(float x) { return 2.0f / (1.0f + __expf(-2.0f * x)) - 1.0f; }

DEVI void gl_lds16(const void* g, void* l) {
  __builtin_amdgcn_global_load_lds((const __attribute__((address_space(1))) void*)g,
                                   (__attribute__((address_space(3))) void*)l,
                                   16, 0, 0);
}

DEVI f32x4 mfma_bf16(bf16x8 a, bf16x8 b, f32x4 c) {
  return __builtin_amdgcn_mfma_f32_16x16x32_bf16(a, b, c, 0, 0, 0);
}
DEVI f32x4 mfma_f16(f16x8 a, f16x8 b, f32x4 c) {
  return __builtin_amdgcn_mfma_f32_16x16x32_f16(a, b, c, 0, 0, 0);
}

// ---------------- converts / gather ----------------

__global__ void cvt_bf16(const float* __restrict__ in, u16* __restrict__ out, int n4) {
  int i = blockIdx.x * 256 + threadIdx.x;
  int stride = gridDim.x * 256;
  for (; i < n4; i += stride) {
    float4 v = ((const float4*)in)[i];
    ushort4 o;
    o.x = f2bf(v.x); o.y = f2bf(v.y); o.z = f2bf(v.z); o.w = f2bf(v.w);
    ((ushort4*)out)[i] = o;
  }
}

__global__ void cvt_f16(const float* __restrict__ in, f16* __restrict__ out, int n4) {
  int i = blockIdx.x * 256 + threadIdx.x;
  int stride = gridDim.x * 256;
  for (; i < n4; i += stride) {
    float4 v = ((const float4*)in)[i];
    f16x4 o = {(f16)v.x, (f16)v.y, (f16)v.z, (f16)v.w};
    ((f16x4*)out)[i] = o;
  }
}

__global__ void cvt_split(const float* __restrict__ in, u16* __restrict__ hi,
                          u16* __restrict__ lo, int n4) {
  int i = blockIdx.x * 256 + threadIdx.x;
  int stride = gridDim.x * 256;
  for (; i < n4; i += stride) {
    float4 v = ((const float4*)in)[i];
    ushort4 h, l;
    split2(v.x, h.x, l.x);
    split2(v.y, h.y, l.y);
    split2(v.z, h.z, l.z);
    split2(v.w, h.w, l.w);
    ((ushort4*)hi)[i] = h;
    ((ushort4*)lo)[i] = l;
  }
}

__global__ void cvt_wi0_split(const float* __restrict__ W, u16* __restrict__ hi,
                              u16* __restrict__ lo) {
  int i = blockIdx.x * 256 + threadIdx.x;
  int stride = gridDim.x * 256;
  for (; i < H3 * EP; i += stride) {
    int r = i / EP, c = i % EP;
    u16 h = 0, l = 0;
    if (c < EE) split2(W[(size_t)r * EE + c], h, l);
    hi[i] = h;
    lo[i] = l;
  }
}

__global__ void gather_x_split(const int* __restrict__ sent, const float* __restrict__ emb,
                               u16* __restrict__ xh, u16* __restrict__ xl) {
  int i = blockIdx.x * 256 + threadIdx.x;
  int stride = gridDim.x * 256;
  for (; i < MM * EP; i += stride) {
    int m = i / EP, c = i % EP;
    int t = m >> 5, b = m & 31;
    int tok = sent[b * SS + t];
    u16 h = 0, l = 0;
    if (c < EE) split2(emb[(size_t)tok * EE + c], h, l);
    xh[i] = h;
    xl[i] = l;
  }
}

// ---------------- GEMM: C[m][n] = A[m][:] . B[n][:] + bias[n] (bf16) --------
// A [MP][lda], B [N][lda] (both K-contiguous), 128x128 tile, BK=64.
// SPLIT: hi/lo planes for both operands, 3 MFMA products (fp32-accurate).

template <bool REMAP, bool SPLIT>
__global__ __launch_bounds__(256) void gemm_bt(const u16* __restrict__ Ah,
                                               const u16* __restrict__ Al, int lda,
                                               const u16* __restrict__ Bh,
                                               const u16* __restrict__ Bl,
                                               const float* __restrict__ bias,
                                               float* __restrict__ out, int out_stride,
                                               int Ksteps, int Mtiles, int Mvalid) {
  __shared__ u16 As[(SPLIT ? 2 : 1) * 128 * 64];
  __shared__ u16 Bs[(SPLIT ? 2 : 1) * 128 * 64];
  const int bid = blockIdx.x;
  const int mtile = bid % Mtiles, ntile = bid / Mtiles;
  const int tid = threadIdx.x;
  const int lane = tid & 63, wave = tid >> 6;
  const int wrow = (wave & 1) * 64, wcol = (wave >> 1) * 64;
  const int l15 = lane & 15, kg = lane >> 4;

  f32x4 acc[4][4];
#pragma unroll
  for (int i = 0; i < 4; ++i)
#pragma unroll
    for (int j = 0; j < 4; ++j) {
      f32x4 z = {0.f, 0.f, 0.f, 0.f};
      acc[i][j] = z;
    }

  for (int ks = 0; ks < Ksteps; ++ks) {
    int k0 = ks * 64;
#pragma unroll
    for (int it = 0; it < 4; ++it) {
      int c = it * 256 + tid;
      int r = c >> 3, kc = (c & 7) * 8;
      gl_lds16(Ah + (size_t)(mtile * 128 + r) * lda + k0 + kc, &As[c * 8]);
      gl_lds16(Bh + (size_t)(ntile * 128 + r) * lda + k0 + kc, &Bs[c * 8]);
      if constexpr (SPLIT) {
        gl_lds16(Al + (size_t)(mtile * 128 + r) * lda + k0 + kc, &As[8192 + c * 8]);
        gl_lds16(Bl + (size_t)(ntile * 128 + r) * lda + k0 + kc, &Bs[8192 + c * 8]);
      }
    }
    __syncthreads();
#pragma unroll
    for (int kk = 0; kk < 2; ++kk) {
      bf16x8 ah[4], bh[4], al[4], bl[4];
#pragma unroll
      for (int i = 0; i < 4; ++i) {
        int ao = (wrow + i * 16 + l15) * 64 + kk * 32 + kg * 8;
        int bo = (wcol + i * 16 + l15) * 64 + kk * 32 + kg * 8;
        ah[i] = *(const bf16x8*)&As[ao];
        bh[i] = *(const bf16x8*)&Bs[bo];
        if constexpr (SPLIT) {
          al[i] = *(const bf16x8*)&As[8192 + ao];
          bl[i] = *(const bf16x8*)&Bs[8192 + bo];
        }
      }
#pragma unroll
      for (int i = 0; i < 4; ++i)
#pragma unroll
        for (int j = 0; j < 4; ++j) {
          f32x4 t = mfma_bf16(ah[i], bh[j], acc[i][j]);
          if constexpr (SPLIT) {
            t = mfma_bf16(ah[i], bl[j], t);
            t = mfma_bf16(al[i], bh[j], t);
          }
          acc[i][j] = t;
        }
    }
    __syncthreads();
  }

  const int r0 = kg * 4;
#pragma unroll
  for (int i = 0; i < 4; ++i) {
    int mbase = mtile * 128 + wrow + i * 16 + r0;
#pragma unroll
    for (int j = 0; j < 4; ++j) {
      int n = ntile * 128 + wcol + j * 16 + l15;
      float bv = bias[n];
#pragma unroll
      for (int reg = 0; reg < 4; ++reg) {
        int m = mbase + reg;
        if (m < Mvalid) {
          float v = acc[i][j][reg] + bv;
          size_t oidx;
          if (REMAP) {
            int b = m & 31, s = m >> 5;
            oidx = ((size_t)(b * TT + s)) * VV + n;
          } else {
            oidx = (size_t)m * out_stride + n;
          }
          out[oidx] = v;
        }
      }
    }
  }
}

// ---------------- recurrence (cooperative, 96 WGs, 64 phases) ----------------
// Exact R3 skeleton; only operand dtype changed to single-plane f16
// (weights 18.9 MB -> 2.3 MB/XCD, L2-resident).

struct RecArgs {
  const f16 *wh0, *wi1, *wh1;
  const float *gx0, *bh0, *bi1, *bh1;
  float *h0f, *h1f;
  f16 *h0x, *h1x;
  u16 *hs;
};

__global__ __launch_bounds__(256, 1) void rec_kernel(RecArgs ra) {
  cg::grid_group grid = cg::this_grid();
  __shared__ float gh[96 * 33];
  const int tid = threadIdx.x;
  const int lane = tid & 63, wave = tid >> 6;
  const int wg = blockIdx.x;
  const bool isL0 = wg < 32;
  const int Jbase = isL0 ? (wg * 32) : ((wg - 32) * 16);
  const int l15 = lane & 15;
  const int kg = lane >> 4;
  const int klo = kg * 8;

  for (int p = 0; p < 64; ++p) {
    const int pb = p & 1, qb = (p + 1) & 1;
    if (isL0) {
      if (p < TT) {
        const int rt = wave >> 1, ct0 = (wave & 1) * 3;
        const f16* ah = ra.h0x + (size_t)qb * (BB * HH) + (size_t)(rt * 16 + l15) * HH + klo;
        const f16* bp[3];
#pragma unroll
        for (int t = 0; t < 3; ++t) {
          int ct = ct0 + t;
          size_t brow = (size_t)((ct >> 1) * HH + Jbase + (ct & 1) * 16 + l15);
          bp[t] = ra.wh0 + brow * HH + klo;
        }
        f32x4 z = {0.f, 0.f, 0.f, 0.f};
        f32x4 acc0 = z, acc1 = z, acc2 = z;
#pragma unroll 4
        for (int kk = 0; kk < 32; ++kk) {
          f16x8 a = *(const f16x8*)(ah + kk * 32);
          acc0 = mfma_f16(a, *(const f16x8*)(bp[0] + kk * 32), acc0);
          acc1 = mfma_f16(a, *(const f16x8*)(bp[1] + kk * 32), acc1);
          acc2 = mfma_f16(a, *(const f16x8*)(bp[2] + kk * 32), acc2);
        }
        f32x4 accs[3] = {acc0, acc1, acc2};
#pragma unroll
        for (int t = 0; t < 3; ++t) {
          int cl = (ct0 + t) * 16 + l15;
#pragma unroll
          for (int r = 0; r < 4; ++r) gh[cl * 33 + rt * 16 + kg * 4 + r] = accs[t][r];
        }
      }
      __syncthreads();
      if (p < TT) {
        const float* hfp = ra.h0f + qb * (BB * HH);
        float* hfc = ra.h0f + pb * (BB * HH);
        f16* hxc = ra.h0x + pb * (BB * HH);
        const float* gx = ra.gx0 + (size_t)p * (BB * H3);
#pragma unroll
        for (int q = 0; q < 4; ++q) {
          int e = q * 256 + tid;
          int j = e >> 5, b = e & 31;
          int gj = Jbase + j;
          float rh = gh[(j)*33 + b] + ra.bh0[gj];
          float zh = gh[(32 + j) * 33 + b] + ra.bh0[HH + gj];
          float nh = gh[(64 + j) * 33 + b] + ra.bh0[2 * HH + gj];
          const float* gxb = gx + (size_t)b * H3;
          float r = sigm(gxb[gj] + rh);
          float zz = sigm(gxb[HH + gj] + zh);
          float n = tanh_(gxb[2 * HH + gj] + r * nh);
          float hp = hfp[b * HH + gj];
          float hn = (1.f - zz) * n + zz * hp;
          hfc[b * HH + gj] = hn;
          hxc[b * HH + gj] = (f16)hn;
        }
      }
    } else {
      if (p >= 1) {
        const int rt = wave >> 1, src = wave & 1;
        const f16* ah = (src ? ra.h1x : ra.h0x) + (size_t)qb * (BB * HH) +
                        (size_t)(rt * 16 + l15) * HH + klo;
        const f16* Bw = src ? ra.wh1 : ra.wi1;
        const f16* bp[3];
#pragma unroll
        for (int g = 0; g < 3; ++g)
          bp[g] = Bw + (size_t)(g * HH + Jbase + l15) * HH + klo;
        f32x4 z = {0.f, 0.f, 0.f, 0.f};
        f32x4 acc0 = z, acc1 = z, acc2 = z;
#pragma unroll 4
        for (int kk = 0; kk < 32; ++kk) {
          f16x8 a = *(const f16x8*)(ah + kk * 32);
          acc0 = mfma_f16(a, *(const f16x8*)(bp[0] + kk * 32), acc0);
          acc1 = mfma_f16(a, *(const f16x8*)(bp[1] + kk * 32), acc1);
          acc2 = mfma_f16(a, *(const f16x8*)(bp[2] + kk * 32), acc2);
        }
        f32x4 accs[3] = {acc0, acc1, acc2};
#pragma unroll
        for (int g = 0; g < 3; ++g) {
          int cl = (src * 3 + g) * 16 + l15;
#pragma unroll
          for (int r = 0; r < 4; ++r) gh[cl * 33 + rt * 16 + kg * 4 + r] = accs[g][r];
        }
      }
      __syncthreads();
      if (p >= 1) {
        const float* hfp = ra.h1f + qb * (BB * HH);
        float* hfc = ra.h1f + pb * (BB * HH);
        f16* hxc = ra.h1x + pb * (BB * HH);
#pragma unroll
        for (int q = 0; q < 2; ++q) {
          int e = q * 256 + tid;
          int j = e >> 5, b = e & 31;
          int gj = Jbase + j;
          float gir = gh[(j)*33 + b] + ra.bi1[gj];
          float giz = gh[(16 + j) * 33 + b] + ra.bi1[HH + gj];
          float gin = gh[(32 + j) * 33 + b] + ra.bi1[2 * HH + gj];
          float ghr = gh[(48 + j) * 33 + b] + ra.bh1[gj];
          float ghz = gh[(64 + j) * 33 + b] + ra.bh1[HH + gj];
          float ghn = gh[(80 + j) * 33 + b] + ra.bh1[2 * HH + gj];
          float r = sigm(gir + ghr);
          float zz = sigm(giz + ghz);
          float n = tanh_(gin + r * ghn);
          float hp = hfp[b * HH + gj];
          float hn = (1.f - zz) * n + zz * hp;
          hfc[b * HH + gj] = hn;
          hxc[b * HH + gj] = (f16)hn;
          ra.hs[((size_t)(p - 1) * BB + b) * HH + gj] = f2bf(hn);
        }
      }
    }
    grid.sync();
  }
}

// ---------------- row reductions + loss ----------------

__global__ __launch_bounds__(256) void rowred_kernel(const float* __restrict__ logits,
                                                     const int* __restrict__ sent,
                                                     const int* __restrict__ length,
                                                     float* __restrict__ tok) {
  __shared__ float red[8];
  const int row = blockIdx.x;  // b*63 + s
  const int b = row / TT, s = row % TT;
  const float* p = logits + (size_t)row * VV;
  const int tid = threadIdx.x;

  float m = -1e30f;
  for (int i = tid; i < VV; i += 256) m = fmaxf(m, p[i]);
  for (int off = 1; off < 64; off <<= 1) m = fmaxf(m, __shfl_xor(m, off));
  if ((tid & 63) == 0) red[tid >> 6] = m;
  __syncthreads();
  m = fmaxf(fmaxf(red[0], red[1]), fmaxf(red[2], red[3]));

  float sum = 0.f;
  for (int i = tid; i < VV; i += 256) sum += __expf(p[i] - m);
  for (int off = 1; off < 64; off <<= 1) sum += __shfl_xor(sum, off);
  if ((tid & 63) == 0) red[4 + (tid >> 6)] = sum;
  __syncthreads();
  if (tid == 0) {
    float tot = red[4] + red[5] + red[6] + red[7];
    float lse = m + __logf(tot);
    int tgt = sent[b * SS + s + 1];
    float tl = p[tgt] - lse;
    if (s >= length[b] - 1) tl = 0.f;
    tok[row] = tl;
  }
}

__global__ void loss_kernel(const float* __restrict__ tok, const int* __restrict__ length,
                            float* __restrict__ out0) {
  int lane = threadIdx.x;
  float v = 0.f;
  if (lane < BB) {
    float s = 0.f;
    for (int t = 0; t < TT; ++t) s += tok[lane * TT + t];
    float ln = (float)(length[lane] - 1);
    v = -s / ln;
  }
  v += __shfl_down(v, 16);
  v += __shfl_down(v, 8);
  v += __shfl_down(v, 4);
  v += __shfl_down(v, 2);
  v += __shfl_down(v, 1);
  if (lane == 0) out0[0] = v / (float)BB;
}

// ---------------- host ----------------

extern "C" void kernel_launch(void* const* d_in, const int* in_sizes, int n_in,
                              void* d_out, int out_size, void* d_ws, size_t ws_size,
                              hipStream_t stream) {
  const int* sent = (const int*)d_in[0];
  const int* length = (const int*)d_in[1];
  const float* emb = (const float*)d_in[2];
  const float* Wi0 = (const float*)d_in[3];
  const float* Wh0 = (const float*)d_in[4];
  const float* bi0 = (const float*)d_in[5];
  const float* bh0 = (const float*)d_in[6];
  const float* Wi1 = (const float*)d_in[7];
  const float* Wh1 = (const float*)d_in[8];
  const float* bi1 = (const float*)d_in[9];
  const float* bh1 = (const float*)d_in[10];
  const float* Wout = (const float*)d_in[11];
  const float* bout = (const float*)d_in[12];
  float* out = (float*)d_out;

  char* ws = (char*)d_ws;
  // Region A: recurrence-phase-only buffers; woutb aliases it after rec.
  size_t offA = 0;
  auto allocA = [&](size_t b) {
    char* p = ws + offA;
    offA = (offA + b + 255) & ~(size_t)255;
    return p;
  };
  f16* wh0f = (f16*)allocA((size_t)H3 * HH * 2);
  f16* wi1f = (f16*)allocA((size_t)H3 * HH * 2);
  f16* wh1f = (f16*)allocA((size_t)H3 * HH * 2);
  u16* wi0h = (u16*)allocA((size_t)H3 * EP * 2);
  u16* wi0l = (u16*)allocA((size_t)H3 * EP * 2);
  u16* xh = (u16*)allocA((size_t)MP * EP * 2);
  u16* xl = (u16*)allocA((size_t)MP * EP * 2);
  float* gx0 = (float*)allocA((size_t)MM * H3 * 4);
  u16* woutb = (u16*)ws;  // alias over region A, used after rec
  size_t wout_bytes = (size_t)VV * HH * 2;
  size_t off = (offA > wout_bytes ? offA : wout_bytes);
  off = (off + 255) & ~(size_t)255;
  auto alloc = [&](size_t b) {
    char* p = ws + off;
    off = (off + b + 255) & ~(size_t)255;
    return p;
  };

  u16* hs = (u16*)alloc((size_t)MP * HH * 2);
  float* h0f = (float*)alloc((size_t)2 * BB * HH * 4);
  float* h1f = (float*)alloc((size_t)2 * BB * HH * 4);
  f16* h0x = (f16*)alloc((size_t)2 * BB * HH * 2);
  f16* h1x = (f16*)alloc((size_t)2 * BB * HH * 2);
  float* tok = (float*)alloc((size_t)MM * 4);

  hipMemsetAsync(h0f, 0, (size_t)2 * BB * HH * 4, stream);
  hipMemsetAsync(h1f, 0, (size_t)2 * BB * HH * 4, stream);
  hipMemsetAsync(h0x, 0, (size_t)2 * BB * HH * 2, stream);
  hipMemsetAsync(h1x, 0, (size_t)2 * BB * HH * 2, stream);
  hipMemsetAsync(hs, 0, (size_t)MP * HH * 2, stream);
  hipMemsetAsync(xh + (size_t)MM * EP, 0, (size_t)(MP - MM) * EP * 2, stream);
  hipMemsetAsync(xl + (size_t)MM * EP, 0, (size_t)(MP - MM) * EP * 2, stream);

  cvt_f16<<<1024, 256, 0, stream>>>(Wh0, wh0f, H3 * HH / 4);
  cvt_f16<<<1024, 256, 0, stream>>>(Wi1, wi1f, H3 * HH / 4);
  cvt_f16<<<1024, 256, 0, stream>>>(Wh1, wh1f, H3 * HH / 4);
  cvt_wi0_split<<<512, 256, 0, stream>>>(Wi0, wi0h, wi0l);
  gather_x_split<<<512, 256, 0, stream>>>(sent, emb, xh, xl);

  gemm_bt<false, true><<<16 * 24, 256, 0, stream>>>(xh, xl, EP, wi0h, wi0l, bi0, gx0, H3,
                                                    5, 16, MM);

  RecArgs ra{wh0f, wi1f, wh1f, gx0, bh0, bi1, bh1, h0f, h1f, h0x, h1x, hs};
  void* kargs[] = {(void*)&ra};
  hipLaunchCooperativeKernel((void*)rec_kernel, dim3(96), dim3(256), kargs, 0, stream);

  // Wout conversion AFTER rec: woutb aliases the (now dead) recurrence weights.
  cvt_bf16<<<2048, 256, 0, stream>>>(Wout, woutb, VV * HH / 4);

  gemm_bt<true, false><<<16 * 250, 256, 0, stream>>>(hs, nullptr, HH, woutb, nullptr, bout,
                                                     out + 1, VV, 16, 16, MM);

  rowred_kernel<<<MM, 256, 0, stream>>>(out + 1, sent, length, tok);
  loss_kernel<<<1, 64, 0, stream>>>(tok, length, out);
}

// Round 6
// 2561.329 us; speedup vs baseline: 1.4380x; 1.0110x over previous
//
#include <hip/hip_runtime.h>
#include <hip/hip_cooperative_groups.h>

namespace cg = cooperative_groups;

typedef unsigned short u16;
typedef unsigned int u32;
typedef _Float16 f16;
typedef __attribute__((ext_vector_type(8))) __bf16 bf16x8;
typedef __attribute__((ext_vector_type(8))) _Float16 f16x8;
typedef __attribute__((ext_vector_type(4))) _Float16 f16x4;
typedef __attribute__((ext_vector_type(4))) float f32x4;

#define DEVI static __device__ __forceinline__

#define BB 32
#define SS 64
#define TT 63
#define VV 32000
#define EE 300
#define EP 320
#define HH 1024
#define H3 3072
#define MM 2016
#define MP 2048

DEVI u16 f2bf(float f) {
  u32 x = __float_as_uint(f);
  u32 r = x + 0x7FFFu + ((x >> 16) & 1u);
  return (u16)(r >> 16);
}
DEVI float bf2f(u16 h) { return __uint_as_float(((u32)h) << 16); }
DEVI void split2(float x, u16& hi, u16& lo) {
  hi = f2bf(x);
  lo = f2bf(x - bf2f(hi));
}
DEVI float sigm(float x) { return 1.0f / (1.0f + __expf(-x)); }
DEVI float tanh_(float x) { return 2.0f / (1.0f + __expf(-2.0f * x)) - 1.0f; }

DEVI void gl_lds16(const void* g, void* l) {
  __builtin_amdgcn_global_load_lds((const __attribute__((address_space(1))) void*)g,
                                   (__attribute__((address_space(3))) void*)l,
                                   16, 0, 0);
}

DEVI f32x4 mfma_bf16(bf16x8 a, bf16x8 b, f32x4 c) {
  return __builtin_amdgcn_mfma_f32_16x16x32_bf16(a, b, c, 0, 0, 0);
}
DEVI f32x4 mfma_f16(f16x8 a, f16x8 b, f32x4 c) {
  return __builtin_amdgcn_mfma_f32_16x16x32_f16(a, b, c, 0, 0, 0);
}

// ---------------- converts / gather ----------------

__global__ void cvt_bf16(const float* __restrict__ in, u16* __restrict__ out, int n4) {
  int i = blockIdx.x * 256 + threadIdx.x;
  int stride = gridDim.x * 256;
  for (; i < n4; i += stride) {
    float4 v = ((const float4*)in)[i];
    ushort4 o;
    o.x = f2bf(v.x); o.y = f2bf(v.y); o.z = f2bf(v.z); o.w = f2bf(v.w);
    ((ushort4*)out)[i] = o;
  }
}

__global__ void cvt_f16(const float* __restrict__ in, f16* __restrict__ out, int n4) {
  int i = blockIdx.x * 256 + threadIdx.x;
  int stride = gridDim.x * 256;
  for (; i < n4; i += stride) {
    float4 v = ((const float4*)in)[i];
    f16x4 o = {(f16)v.x, (f16)v.y, (f16)v.z, (f16)v.w};
    ((f16x4*)out)[i] = o;
  }
}

__global__ void cvt_split(const float* __restrict__ in, u16* __restrict__ hi,
                          u16* __restrict__ lo, int n4) {
  int i = blockIdx.x * 256 + threadIdx.x;
  int stride = gridDim.x * 256;
  for (; i < n4; i += stride) {
    float4 v = ((const float4*)in)[i];
    ushort4 h, l;
    split2(v.x, h.x, l.x);
    split2(v.y, h.y, l.y);
    split2(v.z, h.z, l.z);
    split2(v.w, h.w, l.w);
    ((ushort4*)hi)[i] = h;
    ((ushort4*)lo)[i] = l;
  }
}

__global__ void cvt_wi0_split(const float* __restrict__ W, u16* __restrict__ hi,
                              u16* __restrict__ lo) {
  int i = blockIdx.x * 256 + threadIdx.x;
  int stride = gridDim.x * 256;
  for (; i < H3 * EP; i += stride) {
    int r = i / EP, c = i % EP;
    u16 h = 0, l = 0;
    if (c < EE) split2(W[(size_t)r * EE + c], h, l);
    hi[i] = h;
    lo[i] = l;
  }
}

__global__ void gather_x_split(const int* __restrict__ sent, const float* __restrict__ emb,
                               u16* __restrict__ xh, u16* __restrict__ xl) {
  int i = blockIdx.x * 256 + threadIdx.x;
  int stride = gridDim.x * 256;
  for (; i < MM * EP; i += stride) {
    int m = i / EP, c = i % EP;
    int t = m >> 5, b = m & 31;
    int tok = sent[b * SS + t];
    u16 h = 0, l = 0;
    if (c < EE) split2(emb[(size_t)tok * EE + c], h, l);
    xh[i] = h;
    xl[i] = l;
  }
}

// ---------------- GEMM: C[m][n] = A[m][:] . B[n][:] + bias[n] (bf16) --------

template <bool REMAP, bool SPLIT>
__global__ __launch_bounds__(256) void gemm_bt(const u16* __restrict__ Ah,
                                               const u16* __restrict__ Al, int lda,
                                               const u16* __restrict__ Bh,
                                               const u16* __restrict__ Bl,
                                               const float* __restrict__ bias,
                                               float* __restrict__ out, int out_stride,
                                               int Ksteps, int Mtiles, int Mvalid) {
  __shared__ u16 As[(SPLIT ? 2 : 1) * 128 * 64];
  __shared__ u16 Bs[(SPLIT ? 2 : 1) * 128 * 64];
  const int bid = blockIdx.x;
  const int mtile = bid % Mtiles, ntile = bid / Mtiles;
  const int tid = threadIdx.x;
  const int lane = tid & 63, wave = tid >> 6;
  const int wrow = (wave & 1) * 64, wcol = (wave >> 1) * 64;
  const int l15 = lane & 15, kg = lane >> 4;

  f32x4 acc[4][4];
#pragma unroll
  for (int i = 0; i < 4; ++i)
#pragma unroll
    for (int j = 0; j < 4; ++j) {
      f32x4 z = {0.f, 0.f, 0.f, 0.f};
      acc[i][j] = z;
    }

  for (int ks = 0; ks < Ksteps; ++ks) {
    int k0 = ks * 64;
#pragma unroll
    for (int it = 0; it < 4; ++it) {
      int c = it * 256 + tid;
      int r = c >> 3, kc = (c & 7) * 8;
      gl_lds16(Ah + (size_t)(mtile * 128 + r) * lda + k0 + kc, &As[c * 8]);
      gl_lds16(Bh + (size_t)(ntile * 128 + r) * lda + k0 + kc, &Bs[c * 8]);
      if constexpr (SPLIT) {
        gl_lds16(Al + (size_t)(mtile * 128 + r) * lda + k0 + kc, &As[8192 + c * 8]);
        gl_lds16(Bl + (size_t)(ntile * 128 + r) * lda + k0 + kc, &Bs[8192 + c * 8]);
      }
    }
    __syncthreads();
#pragma unroll
    for (int kk = 0; kk < 2; ++kk) {
      bf16x8 ah[4], bh[4], al[4], bl[4];
#pragma unroll
      for (int i = 0; i < 4; ++i) {
        int ao = (wrow + i * 16 + l15) * 64 + kk * 32 + kg * 8;
        int bo = (wcol + i * 16 + l15) * 64 + kk * 32 + kg * 8;
        ah[i] = *(const bf16x8*)&As[ao];
        bh[i] = *(const bf16x8*)&Bs[bo];
        if constexpr (SPLIT) {
          al[i] = *(const bf16x8*)&As[8192 + ao];
          bl[i] = *(const bf16x8*)&Bs[8192 + bo];
        }
      }
#pragma unroll
      for (int i = 0; i < 4; ++i)
#pragma unroll
        for (int j = 0; j < 4; ++j) {
          f32x4 t = mfma_bf16(ah[i], bh[j], acc[i][j]);
          if constexpr (SPLIT) {
            t = mfma_bf16(ah[i], bl[j], t);
            t = mfma_bf16(al[i], bh[j], t);
          }
          acc[i][j] = t;
        }
    }
    __syncthreads();
  }

  const int r0 = kg * 4;
#pragma unroll
  for (int i = 0; i < 4; ++i) {
    int mbase = mtile * 128 + wrow + i * 16 + r0;
#pragma unroll
    for (int j = 0; j < 4; ++j) {
      int n = ntile * 128 + wcol + j * 16 + l15;
      float bv = bias[n];
#pragma unroll
      for (int reg = 0; reg < 4; ++reg) {
        int m = mbase + reg;
        if (m < Mvalid) {
          float v = acc[i][j][reg] + bv;
          size_t oidx;
          if (REMAP) {
            int b = m & 31, s = m >> 5;
            oidx = ((size_t)(b * TT + s)) * VV + n;
          } else {
            oidx = (size_t)m * out_stride + n;
          }
          out[oidx] = v;
        }
      }
    }
  }
}

// ---------------- recurrence (cooperative, 192 WGs, 64 phases) --------------
// Weights LDS-resident (survive grid.sync's L2 invalidation).
// L0: WGs 0..63, 16 cols each. LDS rows: [r:0-15][z:16-31][n:32-47].
// L1: WGs 64..191, 8 cols each. LDS rows: [gi_r:0-7][gi_z:8-15][gi_n:16-23]
//     [gh_r:24-31][gh_z:32-39][gh_n:40-47]; B-tiles read rows via l15&7
//     (lanes 8-15 duplicate 0-7; D cols 8-15 discarded on store).
// XOR swizzle (both sides): byte ^= (row&7)<<4 within each 2KB row.

struct RecArgs {
  const f16 *wh0, *wi1, *wh1;
  const float *gx0, *bh0, *bi1, *bh1;
  float *h0f, *h1f;
  f16 *h0x, *h1x;
  u16 *hs;
};

__global__ __launch_bounds__(256, 1) void rec_kernel(RecArgs ra) {
  cg::grid_group grid = cg::this_grid();
  __shared__ f16 wlds[48 * 1024];
  __shared__ float gh[48 * 33];
  const int tid = threadIdx.x;
  const int lane = tid & 63, wave = tid >> 6;
  const int wg = blockIdx.x;
  const bool isL0 = wg < 64;
  const int Jbase = isL0 ? (wg * 16) : ((wg - 64) * 8);
  const int l15 = lane & 15;
  const int kg = lane >> 4;
  const int klo = kg * 8;
  const int swz = (l15 & 7) << 4;
  char* wb = (char*)wlds;

  // ---- prologue: stage this WG's weight slice into LDS (swizzled) ----
#pragma unroll
  for (int it = 0; it < 24; ++it) {
    int q = it * 256 + tid;  // 0..6143
    int r = q >> 7;          // LDS row 0..47
    int c16 = q & 127;       // 16B chunk within row
    const f16* gp;
    if (isL0) {
      int gate = r >> 4, colr = r & 15;
      gp = ra.wh0 + ((size_t)(gate * HH + Jbase + colr)) * HH + c16 * 8;
    } else {
      int tile = r >> 3, colr = r & 7;
      int msrc = tile / 3, gate = tile - msrc * 3;
      const f16* W = msrc ? ra.wh1 : ra.wi1;
      gp = W + ((size_t)(gate * HH + Jbase + colr)) * HH + c16 * 8;
    }
    f16x8 v = *(const f16x8*)gp;
    int byte = r * 2048 + ((c16 * 16) ^ ((r & 7) << 4));
    *(f16x8*)(wb + byte) = v;
  }
  __syncthreads();

  for (int p = 0; p < 64; ++p) {
    const int pb = p & 1, qb = (p + 1) & 1;
    if (isL0) {
      if (p < TT) {
        const int rt = wave >> 1, tt = wave & 1;
        const f16* ah =
            ra.h0x + (size_t)qb * (BB * HH) + (size_t)(rt * 16 + l15) * HH + klo;
        f32x4 z = {0.f, 0.f, 0.f, 0.f};
        if (tt == 0) {
          f32x4 acc0 = z, acc1 = z;
#pragma unroll 4
          for (int kk = 0; kk < 32; ++kk) {
            f16x8 a = *(const f16x8*)(ah + kk * 32);
            int inner = (kk * 64 + kg * 16) ^ swz;
            f16x8 b0 = *(const f16x8*)(wb + (0 * 16 + l15) * 2048 + inner);
            f16x8 b1 = *(const f16x8*)(wb + (1 * 16 + l15) * 2048 + inner);
            acc0 = mfma_f16(a, b0, acc0);
            acc1 = mfma_f16(a, b1, acc1);
          }
#pragma unroll
          for (int r = 0; r < 4; ++r) {
            gh[(l15)*33 + rt * 16 + kg * 4 + r] = acc0[r];
            gh[(16 + l15) * 33 + rt * 16 + kg * 4 + r] = acc1[r];
          }
        } else {
          f32x4 acc2 = z;
#pragma unroll 4
          for (int kk = 0; kk < 32; ++kk) {
            f16x8 a = *(const f16x8*)(ah + kk * 32);
            int inner = (kk * 64 + kg * 16) ^ swz;
            f16x8 b2 = *(const f16x8*)(wb + (2 * 16 + l15) * 2048 + inner);
            acc2 = mfma_f16(a, b2, acc2);
          }
#pragma unroll
          for (int r = 0; r < 4; ++r)
            gh[(32 + l15) * 33 + rt * 16 + kg * 4 + r] = acc2[r];
        }
      }
      __syncthreads();
      if (p < TT) {
        const float* hfp = ra.h0f + qb * (BB * HH);
        float* hfc = ra.h0f + pb * (BB * HH);
        f16* hxc = ra.h0x + pb * (BB * HH);
        const float* gx = ra.gx0 + (size_t)p * (BB * H3);
#pragma unroll
        for (int q = 0; q < 2; ++q) {
          int e = q * 256 + tid;
          int j = e >> 5, b = e & 31;
          int gj = Jbase + j;
          float rh = gh[(j)*33 + b] + ra.bh0[gj];
          float zh = gh[(16 + j) * 33 + b] + ra.bh0[HH + gj];
          float nh = gh[(32 + j) * 33 + b] + ra.bh0[2 * HH + gj];
          const float* gxb = gx + (size_t)b * H3;
          float r = sigm(gxb[gj] + rh);
          float zz = sigm(gxb[HH + gj] + zh);
          float n = tanh_(gxb[2 * HH + gj] + r * nh);
          float hp = hfp[b * HH + gj];
          float hn = (1.f - zz) * n + zz * hp;
          hfc[b * HH + gj] = hn;
          hxc[b * HH + gj] = (f16)hn;
        }
      }
    } else {
      if (p >= 1) {
        const int rt = wave >> 1, src = wave & 1;
        const f16* ah = (src ? ra.h1x : ra.h0x) + (size_t)qb * (BB * HH) +
                        (size_t)(rt * 16 + l15) * HH + klo;
        const int rowb = src * 24 + (l15 & 7);  // tile base rows: src*3 tiles of 8
        f32x4 z = {0.f, 0.f, 0.f, 0.f};
        f32x4 acc0 = z, acc1 = z, acc2 = z;
#pragma unroll 4
        for (int kk = 0; kk < 32; ++kk) {
          f16x8 a = *(const f16x8*)(ah + kk * 32);
          int inner = (kk * 64 + kg * 16) ^ swz;
          f16x8 b0 = *(const f16x8*)(wb + (rowb + 0) * 2048 + inner);
          f16x8 b1 = *(const f16x8*)(wb + (rowb + 8) * 2048 + inner);
          f16x8 b2 = *(const f16x8*)(wb + (rowb + 16) * 2048 + inner);
          acc0 = mfma_f16(a, b0, acc0);
          acc1 = mfma_f16(a, b1, acc1);
          acc2 = mfma_f16(a, b2, acc2);
        }
        if (l15 < 8) {
          f32x4 accs[3] = {acc0, acc1, acc2};
#pragma unroll
          for (int g = 0; g < 3; ++g) {
            int cl = (src * 3 + g) * 8 + l15;
#pragma unroll
            for (int r = 0; r < 4; ++r)
              gh[cl * 33 + rt * 16 + kg * 4 + r] = accs[g][r];
          }
        }
      }
      __syncthreads();
      if (p >= 1) {
        const float* hfp = ra.h1f + qb * (BB * HH);
        float* hfc = ra.h1f + pb * (BB * HH);
        f16* hxc = ra.h1x + pb * (BB * HH);
        int j = tid >> 5, b = tid & 31;
        int gj = Jbase + j;
        float gir = gh[(j)*33 + b] + ra.bi1[gj];
        float giz = gh[(8 + j) * 33 + b] + ra.bi1[HH + gj];
        float gin = gh[(16 + j) * 33 + b] + ra.bi1[2 * HH + gj];
        float ghr = gh[(24 + j) * 33 + b] + ra.bh1[gj];
        float ghz = gh[(32 + j) * 33 + b] + ra.bh1[HH + gj];
        float ghn = gh[(40 + j) * 33 + b] + ra.bh1[2 * HH + gj];
        float r = sigm(gir + ghr);
        float zz = sigm(giz + ghz);
        float n = tanh_(gin + r * ghn);
        float hp = hfp[b * HH + gj];
        float hn = (1.f - zz) * n + zz * hp;
        hfc[b * HH + gj] = hn;
        hxc[b * HH + gj] = (f16)hn;
        ra.hs[((size_t)(p - 1) * BB + b) * HH + gj] = f2bf(hn);
      }
    }
    grid.sync();
  }
}

// ---------------- row reductions + loss ----------------

__global__ __launch_bounds__(256) void rowred_kernel(const float* __restrict__ logits,
                                                     const int* __restrict__ sent,
                                                     const int* __restrict__ length,
                                                     float* __restrict__ tok) {
  __shared__ float red[8];
  const int row = blockIdx.x;  // b*63 + s
  const int b = row / TT, s = row % TT;
  const float* p = logits + (size_t)row * VV;
  const int tid = threadIdx.x;

  float m = -1e30f;
  for (int i = tid; i < VV; i += 256) m = fmaxf(m, p[i]);
  for (int off = 1; off < 64; off <<= 1) m = fmaxf(m, __shfl_xor(m, off));
  if ((tid & 63) == 0) red[tid >> 6] = m;
  __syncthreads();
  m = fmaxf(fmaxf(red[0], red[1]), fmaxf(red[2], red[3]));

  float sum = 0.f;
  for (int i = tid; i < VV; i += 256) sum += __expf(p[i] - m);
  for (int off = 1; off < 64; off <<= 1) sum += __shfl_xor(sum, off);
  if ((tid & 63) == 0) red[4 + (tid >> 6)] = sum;
  __syncthreads();
  if (tid == 0) {
    float tot = red[4] + red[5] + red[6] + red[7];
    float lse = m + __logf(tot);
    int tgt = sent[b * SS + s + 1];
    float tl = p[tgt] - lse;
    if (s >= length[b] - 1) tl = 0.f;
    tok[row] = tl;
  }
}

__global__ void loss_kernel(const float* __restrict__ tok, const int* __restrict__ length,
                            float* __restrict__ out0) {
  int lane = threadIdx.x;
  float v = 0.f;
  if (lane < BB) {
    float s = 0.f;
    for (int t = 0; t < TT; ++t) s += tok[lane * TT + t];
    float ln = (float)(length[lane] - 1);
    v = -s / ln;
  }
  v += __shfl_down(v, 16);
  v += __shfl_down(v, 8);
  v += __shfl_down(v, 4);
  v += __shfl_down(v, 2);
  v += __shfl_down(v, 1);
  if (lane == 0) out0[0] = v / (float)BB;
}

// ---------------- host ----------------

extern "C" void kernel_launch(void* const* d_in, const int* in_sizes, int n_in,
                              void* d_out, int out_size, void* d_ws, size_t ws_size,
                              hipStream_t stream) {
  const int* sent = (const int*)d_in[0];
  const int* length = (const int*)d_in[1];
  const float* emb = (const float*)d_in[2];
  const float* Wi0 = (const float*)d_in[3];
  const float* Wh0 = (const float*)d_in[4];
  const float* bi0 = (const float*)d_in[5];
  const float* bh0 = (const float*)d_in[6];
  const float* Wi1 = (const float*)d_in[7];
  const float* Wh1 = (const float*)d_in[8];
  const float* bi1 = (const float*)d_in[9];
  const float* bh1 = (const float*)d_in[10];
  const float* Wout = (const float*)d_in[11];
  const float* bout = (const float*)d_in[12];
  float* out = (float*)d_out;

  char* ws = (char*)d_ws;
  // Region A: recurrence-phase-only buffers; woutb aliases it after rec.
  size_t offA = 0;
  auto allocA = [&](size_t b) {
    char* p = ws + offA;
    offA = (offA + b + 255) & ~(size_t)255;
    return p;
  };
  f16* wh0f = (f16*)allocA((size_t)H3 * HH * 2);
  f16* wi1f = (f16*)allocA((size_t)H3 * HH * 2);
  f16* wh1f = (f16*)allocA((size_t)H3 * HH * 2);
  u16* wi0h = (u16*)allocA((size_t)H3 * EP * 2);
  u16* wi0l = (u16*)allocA((size_t)H3 * EP * 2);
  u16* xh = (u16*)allocA((size_t)MP * EP * 2);
  u16* xl = (u16*)allocA((size_t)MP * EP * 2);
  float* gx0 = (float*)allocA((size_t)MM * H3 * 4);
  u16* woutb = (u16*)ws;  // alias over region A, used after rec
  size_t wout_bytes = (size_t)VV * HH * 2;
  size_t off = (offA > wout_bytes ? offA : wout_bytes);
  off = (off + 255) & ~(size_t)255;
  auto alloc = [&](size_t b) {
    char* p = ws + off;
    off = (off + b + 255) & ~(size_t)255;
    return p;
  };

  u16* hs = (u16*)alloc((size_t)MP * HH * 2);
  float* h0f = (float*)alloc((size_t)2 * BB * HH * 4);
  float* h1f = (float*)alloc((size_t)2 * BB * HH * 4);
  f16* h0x = (f16*)alloc((size_t)2 * BB * HH * 2);
  f16* h1x = (f16*)alloc((size_t)2 * BB * HH * 2);
  float* tok = (float*)alloc((size_t)MM * 4);

  hipMemsetAsync(h0f, 0, (size_t)2 * BB * HH * 4, stream);
  hipMemsetAsync(h1f, 0, (size_t)2 * BB * HH * 4, stream);
  hipMemsetAsync(h0x, 0, (size_t)2 * BB * HH * 2, stream);
  hipMemsetAsync(h1x, 0, (size_t)2 * BB * HH * 2, stream);
  hipMemsetAsync(hs, 0, (size_t)MP * HH * 2, stream);
  hipMemsetAsync(xh + (size_t)MM * EP, 0, (size_t)(MP - MM) * EP * 2, stream);
  hipMemsetAsync(xl + (size_t)MM * EP, 0, (size_t)(MP - MM) * EP * 2, stream);

  cvt_f16<<<1024, 256, 0, stream>>>(Wh0, wh0f, H3 * HH / 4);
  cvt_f16<<<1024, 256, 0, stream>>>(Wi1, wi1f, H3 * HH / 4);
  cvt_f16<<<1024, 256, 0, stream>>>(Wh1, wh1f, H3 * HH / 4);
  cvt_wi0_split<<<512, 256, 0, stream>>>(Wi0, wi0h, wi0l);
  gather_x_split<<<512, 256, 0, stream>>>(sent, emb, xh, xl);

  gemm_bt<false, true><<<16 * 24, 256, 0, stream>>>(xh, xl, EP, wi0h, wi0l, bi0, gx0, H3,
                                                    5, 16, MM);

  RecArgs ra{wh0f, wi1f, wh1f, gx0, bh0, bi1, bh1, h0f, h1f, h0x, h1x, hs};
  void* kargs[] = {(void*)&ra};
  hipLaunchCooperativeKernel((void*)rec_kernel, dim3(192), dim3(256), kargs, 0, stream);

  // Wout conversion AFTER rec: woutb aliases the (now dead) recurrence weights.
  cvt_bf16<<<2048, 256, 0, stream>>>(Wout, woutb, VV * HH / 4);

  gemm_bt<true, false><<<16 * 250, 256, 0, stream>>>(hs, nullptr, HH, woutb, nullptr, bout,
                                                     out + 1, VV, 16, 16, MM);

  rowred_kernel<<<MM, 256, 0, stream>>>(out + 1, sent, length, tok);
  loss_kernel<<<1, 64, 0, stream>>>(tok, length, out);
}

// Round 7
// 1577.643 us; speedup vs baseline: 2.3347x; 1.6235x over previous
//
#include <hip/hip_runtime.h>

typedef unsigned short u16;
typedef unsigned int u32;
typedef unsigned long long u64;
typedef _Float16 f16;
typedef __attribute__((ext_vector_type(8))) __bf16 bf16x8;
typedef __attribute__((ext_vector_type(8))) _Float16 f16x8;
typedef __attribute__((ext_vector_type(4))) _Float16 f16x4;
typedef __attribute__((ext_vector_type(4))) float f32x4;

#define DEVI static __device__ __forceinline__

#define BB 32
#define SS 64
#define TT 63
#define VV 32000
#define EE 300
#define EP 320
#define HH 1024
#define H3 3072
#define MM 2016
#define MP 2048
#define NWG 192

DEVI u16 f2bf(float f) {
  u32 x = __float_as_uint(f);
  u32 r = x + 0x7FFFu + ((x >> 16) & 1u);
  return (u16)(r >> 16);
}
DEVI float bf2f(u16 h) { return __uint_as_float(((u32)h) << 16); }
DEVI void split2(float x, u16& hi, u16& lo) {
  hi = f2bf(x);
  lo = f2bf(x - bf2f(hi));
}
DEVI float sigm(float x) { return 1.0f / (1.0f + __expf(-x)); }
DEVI float tanh_(float x) { return 2.0f / (1.0f + __expf(-2.0f * x)) - 1.0f; }

DEVI void gl_lds16(const void* g, void* l) {
  __builtin_amdgcn_global_load_lds((const __attribute__((address_space(1))) void*)g,
                                   (__attribute__((address_space(3))) void*)l,
                                   16, 0, 0);
}

DEVI f32x4 mfma_bf16(bf16x8 a, bf16x8 b, f32x4 c) {
  return __builtin_amdgcn_mfma_f32_16x16x32_bf16(a, b, c, 0, 0, 0);
}
DEVI f32x4 mfma_f16(f16x8 a, f16x8 b, f32x4 c) {
  return __builtin_amdgcn_mfma_f32_16x16x32_f16(a, b, c, 0, 0, 0);
}

// Device-scope (IF$-coherent, sc1) accesses for cross-XCD h-state exchange.
DEVI f16x8 ald16(const f16* p) {
  union { u64 u[2]; f16x8 v; } t;
  const u64* q = (const u64*)p;
  t.u[0] = __hip_atomic_load(q, __ATOMIC_RELAXED, __HIP_MEMORY_SCOPE_AGENT);
  t.u[1] = __hip_atomic_load(q + 1, __ATOMIC_RELAXED, __HIP_MEMORY_SCOPE_AGENT);
  return t.v;
}
DEVI void ast32(u32* p, u32 v) {
  __hip_atomic_store(p, v, __ATOMIC_RELAXED, __HIP_MEMORY_SCOPE_AGENT);
}

// Cache-neutral grid barrier: all cross-WG data already at IF$ via sc1 ops;
// __syncthreads drains vmcnt (stores ACKed) before the signal. No L2 flush.
DEVI void gbar(u32* bar, int idx) {
  __syncthreads();
  if (threadIdx.x == 0) {
    u32* c = bar + idx * 16;
    __hip_atomic_fetch_add(c, 1u, __ATOMIC_RELAXED, __HIP_MEMORY_SCOPE_AGENT);
    while (__hip_atomic_load(c, __ATOMIC_RELAXED, __HIP_MEMORY_SCOPE_AGENT) < NWG)
      __builtin_amdgcn_s_sleep(1);
  }
  __syncthreads();
}

// ---------------- converts / gather ----------------

__global__ void cvt_bf16(const float* __restrict__ in, u16* __restrict__ out, int n4) {
  int i = blockIdx.x * 256 + threadIdx.x;
  int stride = gridDim.x * 256;
  for (; i < n4; i += stride) {
    float4 v = ((const float4*)in)[i];
    ushort4 o;
    o.x = f2bf(v.x); o.y = f2bf(v.y); o.z = f2bf(v.z); o.w = f2bf(v.w);
    ((ushort4*)out)[i] = o;
  }
}

__global__ void cvt_f16(const float* __restrict__ in, f16* __restrict__ out, int n4) {
  int i = blockIdx.x * 256 + threadIdx.x;
  int stride = gridDim.x * 256;
  for (; i < n4; i += stride) {
    float4 v = ((const float4*)in)[i];
    f16x4 o = {(f16)v.x, (f16)v.y, (f16)v.z, (f16)v.w};
    ((f16x4*)out)[i] = o;
  }
}

__global__ void cvt_split(const float* __restrict__ in, u16* __restrict__ hi,
                          u16* __restrict__ lo, int n4) {
  int i = blockIdx.x * 256 + threadIdx.x;
  int stride = gridDim.x * 256;
  for (; i < n4; i += stride) {
    float4 v = ((const float4*)in)[i];
    ushort4 h, l;
    split2(v.x, h.x, l.x);
    split2(v.y, h.y, l.y);
    split2(v.z, h.z, l.z);
    split2(v.w, h.w, l.w);
    ((ushort4*)hi)[i] = h;
    ((ushort4*)lo)[i] = l;
  }
}

__global__ void cvt_wi0_split(const float* __restrict__ W, u16* __restrict__ hi,
                              u16* __restrict__ lo) {
  int i = blockIdx.x * 256 + threadIdx.x;
  int stride = gridDim.x * 256;
  for (; i < H3 * EP; i += stride) {
    int r = i / EP, c = i % EP;
    u16 h = 0, l = 0;
    if (c < EE) split2(W[(size_t)r * EE + c], h, l);
    hi[i] = h;
    lo[i] = l;
  }
}

__global__ void gather_x_split(const int* __restrict__ sent, const float* __restrict__ emb,
                               u16* __restrict__ xh, u16* __restrict__ xl) {
  int i = blockIdx.x * 256 + threadIdx.x;
  int stride = gridDim.x * 256;
  for (; i < MM * EP; i += stride) {
    int m = i / EP, c = i % EP;
    int t = m >> 5, b = m & 31;
    int tok = sent[b * SS + t];
    u16 h = 0, l = 0;
    if (c < EE) split2(emb[(size_t)tok * EE + c], h, l);
    xh[i] = h;
    xl[i] = l;
  }
}

// ---------------- GEMM: C[m][n] = A[m][:] . B[n][:] + bias[n] (bf16) --------

template <bool REMAP, bool SPLIT>
__global__ __launch_bounds__(256) void gemm_bt(const u16* __restrict__ Ah,
                                               const u16* __restrict__ Al, int lda,
                                               const u16* __restrict__ Bh,
                                               const u16* __restrict__ Bl,
                                               const float* __restrict__ bias,
                                               float* __restrict__ out, int out_stride,
                                               int Ksteps, int Mtiles, int Mvalid) {
  __shared__ u16 As[(SPLIT ? 2 : 1) * 128 * 64];
  __shared__ u16 Bs[(SPLIT ? 2 : 1) * 128 * 64];
  const int bid = blockIdx.x;
  const int mtile = bid % Mtiles, ntile = bid / Mtiles;
  const int tid = threadIdx.x;
  const int lane = tid & 63, wave = tid >> 6;
  const int wrow = (wave & 1) * 64, wcol = (wave >> 1) * 64;
  const int l15 = lane & 15, kg = lane >> 4;

  f32x4 acc[4][4];
#pragma unroll
  for (int i = 0; i < 4; ++i)
#pragma unroll
    for (int j = 0; j < 4; ++j) {
      f32x4 z = {0.f, 0.f, 0.f, 0.f};
      acc[i][j] = z;
    }

  for (int ks = 0; ks < Ksteps; ++ks) {
    int k0 = ks * 64;
#pragma unroll
    for (int it = 0; it < 4; ++it) {
      int c = it * 256 + tid;
      int r = c >> 3, kc = (c & 7) * 8;
      gl_lds16(Ah + (size_t)(mtile * 128 + r) * lda + k0 + kc, &As[c * 8]);
      gl_lds16(Bh + (size_t)(ntile * 128 + r) * lda + k0 + kc, &Bs[c * 8]);
      if constexpr (SPLIT) {
        gl_lds16(Al + (size_t)(mtile * 128 + r) * lda + k0 + kc, &As[8192 + c * 8]);
        gl_lds16(Bl + (size_t)(ntile * 128 + r) * lda + k0 + kc, &Bs[8192 + c * 8]);
      }
    }
    __syncthreads();
#pragma unroll
    for (int kk = 0; kk < 2; ++kk) {
      bf16x8 ah[4], bh[4], al[4], bl[4];
#pragma unroll
      for (int i = 0; i < 4; ++i) {
        int ao = (wrow + i * 16 + l15) * 64 + kk * 32 + kg * 8;
        int bo = (wcol + i * 16 + l15) * 64 + kk * 32 + kg * 8;
        ah[i] = *(const bf16x8*)&As[ao];
        bh[i] = *(const bf16x8*)&Bs[bo];
        if constexpr (SPLIT) {
          al[i] = *(const bf16x8*)&As[8192 + ao];
          bl[i] = *(const bf16x8*)&Bs[8192 + bo];
        }
      }
#pragma unroll
      for (int i = 0; i < 4; ++i)
#pragma unroll
        for (int j = 0; j < 4; ++j) {
          f32x4 t = mfma_bf16(ah[i], bh[j], acc[i][j]);
          if constexpr (SPLIT) {
            t = mfma_bf16(ah[i], bl[j], t);
            t = mfma_bf16(al[i], bh[j], t);
          }
          acc[i][j] = t;
        }
    }
    __syncthreads();
  }

  const int r0 = kg * 4;
#pragma unroll
  for (int i = 0; i < 4; ++i) {
    int mbase = mtile * 128 + wrow + i * 16 + r0;
#pragma unroll
    for (int j = 0; j < 4; ++j) {
      int n = ntile * 128 + wcol + j * 16 + l15;
      float bv = bias[n];
#pragma unroll
      for (int reg = 0; reg < 4; ++reg) {
        int m = mbase + reg;
        if (m < Mvalid) {
          float v = acc[i][j][reg] + bv;
          size_t oidx;
          if (REMAP) {
            int b = m & 31, s = m >> 5;
            oidx = ((size_t)(b * TT + s)) * VV + n;
          } else {
            oidx = (size_t)m * out_stride + n;
          }
          out[oidx] = v;
        }
      }
    }
  }
}

// ---------------- recurrence (192 WGs, 64 phases, custom IF$ barrier) -------
// Weights LDS-resident. Cross-XCD h-state via device-scope relaxed atomics
// (sc1, coherent at Infinity Cache) -> no L2 writeback/invalidate per phase.
// L0: WGs 0..63, 16 cols each. LDS rows: [r:0-15][z:16-31][n:32-47].
// L1: WGs 64..191, 8 cols each. LDS rows: [gi_r][gi_z][gi_n][gh_r][gh_z][gh_n]
//     x8; B-tiles read rows via l15&7 (lanes 8-15 dup; D cols 8-15 dropped).
// XOR swizzle (both sides): byte ^= (row&7)<<4 within each 2KB row.

struct RecArgs {
  const f16 *wh0, *wi1, *wh1;
  const float *gx0, *bh0, *bi1, *bh1;
  float *h0f, *h1f;
  f16 *h0x, *h1x;
  u16 *hs;
  u32 *bar;
};

__global__ __launch_bounds__(256, 1) void rec_kernel(RecArgs ra) {
  __shared__ f16 wlds[48 * 1024];
  __shared__ float gh[48 * 33];
  const int tid = threadIdx.x;
  const int lane = tid & 63, wave = tid >> 6;
  const int wg = blockIdx.x;
  const bool isL0 = wg < 64;
  const int Jbase = isL0 ? (wg * 16) : ((wg - 64) * 8);
  const int l15 = lane & 15;
  const int kg = lane >> 4;
  const int klo = kg * 8;
  const int swz = (l15 & 7) << 4;
  char* wb = (char*)wlds;

  // ---- prologue: stage this WG's weight slice into LDS (swizzled) ----
#pragma unroll
  for (int it = 0; it < 24; ++it) {
    int q = it * 256 + tid;  // 0..6143
    int r = q >> 7;          // LDS row 0..47
    int c16 = q & 127;       // 16B chunk within row
    const f16* gp;
    if (isL0) {
      int gate = r >> 4, colr = r & 15;
      gp = ra.wh0 + ((size_t)(gate * HH + Jbase + colr)) * HH + c16 * 8;
    } else {
      int tile = r >> 3, colr = r & 7;
      int msrc = tile / 3, gate = tile - msrc * 3;
      const f16* W = msrc ? ra.wh1 : ra.wi1;
      gp = W + ((size_t)(gate * HH + Jbase + colr)) * HH + c16 * 8;
    }
    f16x8 v = *(const f16x8*)gp;
    int byte = r * 2048 + ((c16 * 16) ^ ((r & 7) << 4));
    *(f16x8*)(wb + byte) = v;
  }
  __syncthreads();

  for (int p = 0; p < 64; ++p) {
    const int pb = p & 1, qb = (p + 1) & 1;
    if (isL0) {
      if (p < TT) {
        const int rt = wave >> 1, tt = wave & 1;
        const f16* ah =
            ra.h0x + (size_t)qb * (BB * HH) + (size_t)(rt * 16 + l15) * HH + klo;
        f32x4 z = {0.f, 0.f, 0.f, 0.f};
        if (tt == 0) {
          f32x4 acc0 = z, acc1 = z;
#pragma unroll 4
          for (int kk = 0; kk < 32; ++kk) {
            f16x8 a = ald16(ah + kk * 32);
            int inner = (kk * 64 + kg * 16) ^ swz;
            f16x8 b0 = *(const f16x8*)(wb + (0 * 16 + l15) * 2048 + inner);
            f16x8 b1 = *(const f16x8*)(wb + (1 * 16 + l15) * 2048 + inner);
            acc0 = mfma_f16(a, b0, acc0);
            acc1 = mfma_f16(a, b1, acc1);
          }
#pragma unroll
          for (int r = 0; r < 4; ++r) {
            gh[(l15)*33 + rt * 16 + kg * 4 + r] = acc0[r];
            gh[(16 + l15) * 33 + rt * 16 + kg * 4 + r] = acc1[r];
          }
        } else {
          f32x4 acc2 = z;
#pragma unroll 4
          for (int kk = 0; kk < 32; ++kk) {
            f16x8 a = ald16(ah + kk * 32);
            int inner = (kk * 64 + kg * 16) ^ swz;
            f16x8 b2 = *(const f16x8*)(wb + (2 * 16 + l15) * 2048 + inner);
            acc2 = mfma_f16(a, b2, acc2);
          }
#pragma unroll
          for (int r = 0; r < 4; ++r)
            gh[(32 + l15) * 33 + rt * 16 + kg * 4 + r] = acc2[r];
        }
      }
      __syncthreads();
      if (p < TT) {
        const float* hfp = ra.h0f + qb * (BB * HH);
        float* hfc = ra.h0f + pb * (BB * HH);
        f16* hxc = ra.h0x + pb * (BB * HH);
        const float* gx = ra.gx0 + (size_t)p * (BB * H3);
        const int b = tid & 31, jp = tid >> 5;  // jp 0..7, j = 2jp,2jp+1
        const int j0 = jp * 2;
        float hn2[2];
#pragma unroll
        for (int s = 0; s < 2; ++s) {
          int j = j0 + s, gj = Jbase + j;
          float rh = gh[(j)*33 + b] + ra.bh0[gj];
          float zh = gh[(16 + j) * 33 + b] + ra.bh0[HH + gj];
          float nh = gh[(32 + j) * 33 + b] + ra.bh0[2 * HH + gj];
          const float* gxb = gx + (size_t)b * H3;
          float r = sigm(gxb[gj] + rh);
          float zz = sigm(gxb[HH + gj] + zh);
          float n = tanh_(gxb[2 * HH + gj] + r * nh);
          float hp = hfp[b * HH + gj];
          hn2[s] = (1.f - zz) * n + zz * hp;
          hfc[b * HH + gj] = hn2[s];
        }
        union { f16 h[2]; u32 u; } pk;
        pk.h[0] = (f16)hn2[0];
        pk.h[1] = (f16)hn2[1];
        ast32((u32*)&hxc[b * HH + Jbase + j0], pk.u);
      }
    } else {
      if (p >= 1) {
        const int rt = wave >> 1, src = wave & 1;
        const f16* ah = (src ? ra.h1x : ra.h0x) + (size_t)qb * (BB * HH) +
                        (size_t)(rt * 16 + l15) * HH + klo;
        const int rowb = src * 24 + (l15 & 7);
        f32x4 z = {0.f, 0.f, 0.f, 0.f};
        f32x4 acc0 = z, acc1 = z, acc2 = z;
#pragma unroll 4
        for (int kk = 0; kk < 32; ++kk) {
          f16x8 a = ald16(ah + kk * 32);
          int inner = (kk * 64 + kg * 16) ^ swz;
          f16x8 b0 = *(const f16x8*)(wb + (rowb + 0) * 2048 + inner);
          f16x8 b1 = *(const f16x8*)(wb + (rowb + 8) * 2048 + inner);
          f16x8 b2 = *(const f16x8*)(wb + (rowb + 16) * 2048 + inner);
          acc0 = mfma_f16(a, b0, acc0);
          acc1 = mfma_f16(a, b1, acc1);
          acc2 = mfma_f16(a, b2, acc2);
        }
        if (l15 < 8) {
          f32x4 accs[3] = {acc0, acc1, acc2};
#pragma unroll
          for (int g = 0; g < 3; ++g) {
            int cl = (src * 3 + g) * 8 + l15;
#pragma unroll
            for (int r = 0; r < 4; ++r)
              gh[cl * 33 + rt * 16 + kg * 4 + r] = accs[g][r];
          }
        }
      }
      __syncthreads();
      if (p >= 1 && tid < 128) {
        const float* hfp = ra.h1f + qb * (BB * HH);
        float* hfc = ra.h1f + pb * (BB * HH);
        f16* hxc = ra.h1x + pb * (BB * HH);
        const int b = tid & 31, jp = tid >> 5;  // jp 0..3, j = 2jp,2jp+1
        const int j0 = jp * 2;
        float hn2[2];
#pragma unroll
        for (int s = 0; s < 2; ++s) {
          int j = j0 + s, gj = Jbase + j;
          float gir = gh[(j)*33 + b] + ra.bi1[gj];
          float giz = gh[(8 + j) * 33 + b] + ra.bi1[HH + gj];
          float gin = gh[(16 + j) * 33 + b] + ra.bi1[2 * HH + gj];
          float ghr = gh[(24 + j) * 33 + b] + ra.bh1[gj];
          float ghz = gh[(32 + j) * 33 + b] + ra.bh1[HH + gj];
          float ghn = gh[(40 + j) * 33 + b] + ra.bh1[2 * HH + gj];
          float r = sigm(gir + ghr);
          float zz = sigm(giz + ghz);
          float n = tanh_(gin + r * ghn);
          float hp = hfp[b * HH + gj];
          hn2[s] = (1.f - zz) * n + zz * hp;
          hfc[b * HH + gj] = hn2[s];
        }
        union { f16 h[2]; u32 u; } pk;
        pk.h[0] = (f16)hn2[0];
        pk.h[1] = (f16)hn2[1];
        ast32((u32*)&hxc[b * HH + Jbase + j0], pk.u);
        union { u16 h[2]; u32 u; } pb2;
        pb2.h[0] = f2bf(hn2[0]);
        pb2.h[1] = f2bf(hn2[1]);
        *(u32*)&ra.hs[((size_t)(p - 1) * BB + b) * HH + Jbase + j0] = pb2.u;
      }
    }
    if (p < 63) gbar(ra.bar, p);
  }
}

// ---------------- row reductions + loss ----------------

__global__ __launch_bounds__(256) void rowred_kernel(const float* __restrict__ logits,
                                                     const int* __restrict__ sent,
                                                     const int* __restrict__ length,
                                                     float* __restrict__ tok) {
  __shared__ float red[8];
  const int row = blockIdx.x;  // b*63 + s
  const int b = row / TT, s = row % TT;
  const float* p = logits + (size_t)row * VV;
  const int tid = threadIdx.x;

  float m = -1e30f;
  for (int i = tid; i < VV; i += 256) m = fmaxf(m, p[i]);
  for (int off = 1; off < 64; off <<= 1) m = fmaxf(m, __shfl_xor(m, off));
  if ((tid & 63) == 0) red[tid >> 6] = m;
  __syncthreads();
  m = fmaxf(fmaxf(red[0], red[1]), fmaxf(red[2], red[3]));

  float sum = 0.f;
  for (int i = tid; i < VV; i += 256) sum += __expf(p[i] - m);
  for (int off = 1; off < 64; off <<= 1) sum += __shfl_xor(sum, off);
  if ((tid & 63) == 0) red[4 + (tid >> 6)] = sum;
  __syncthreads();
  if (tid == 0) {
    float tot = red[4] + red[5] + red[6] + red[7];
    float lse = m + __logf(tot);
    int tgt = sent[b * SS + s + 1];
    float tl = p[tgt] - lse;
    if (s >= length[b] - 1) tl = 0.f;
    tok[row] = tl;
  }
}

__global__ void loss_kernel(const float* __restrict__ tok, const int* __restrict__ length,
                            float* __restrict__ out0) {
  int lane = threadIdx.x;
  float v = 0.f;
  if (lane < BB) {
    float s = 0.f;
    for (int t = 0; t < TT; ++t) s += tok[lane * TT + t];
    float ln = (float)(length[lane] - 1);
    v = -s / ln;
  }
  v += __shfl_down(v, 16);
  v += __shfl_down(v, 8);
  v += __shfl_down(v, 4);
  v += __shfl_down(v, 2);
  v += __shfl_down(v, 1);
  if (lane == 0) out0[0] = v / (float)BB;
}

// ---------------- host ----------------

extern "C" void kernel_launch(void* const* d_in, const int* in_sizes, int n_in,
                              void* d_out, int out_size, void* d_ws, size_t ws_size,
                              hipStream_t stream) {
  const int* sent = (const int*)d_in[0];
  const int* length = (const int*)d_in[1];
  const float* emb = (const float*)d_in[2];
  const float* Wi0 = (const float*)d_in[3];
  const float* Wh0 = (const float*)d_in[4];
  const float* bi0 = (const float*)d_in[5];
  const float* bh0 = (const float*)d_in[6];
  const float* Wi1 = (const float*)d_in[7];
  const float* Wh1 = (const float*)d_in[8];
  const float* bi1 = (const float*)d_in[9];
  const float* bh1 = (const float*)d_in[10];
  const float* Wout = (const float*)d_in[11];
  const float* bout = (const float*)d_in[12];
  float* out = (float*)d_out;

  char* ws = (char*)d_ws;
  // Region A: recurrence-phase-only buffers; woutb aliases it after rec.
  size_t offA = 0;
  auto allocA = [&](size_t b) {
    char* p = ws + offA;
    offA = (offA + b + 255) & ~(size_t)255;
    return p;
  };
  f16* wh0f = (f16*)allocA((size_t)H3 * HH * 2);
  f16* wi1f = (f16*)allocA((size_t)H3 * HH * 2);
  f16* wh1f = (f16*)allocA((size_t)H3 * HH * 2);
  u16* wi0h = (u16*)allocA((size_t)H3 * EP * 2);
  u16* wi0l = (u16*)allocA((size_t)H3 * EP * 2);
  u16* xh = (u16*)allocA((size_t)MP * EP * 2);
  u16* xl = (u16*)allocA((size_t)MP * EP * 2);
  float* gx0 = (float*)allocA((size_t)MM * H3 * 4);
  u16* woutb = (u16*)ws;  // alias over region A, used after rec
  size_t wout_bytes = (size_t)VV * HH * 2;
  size_t off = (offA > wout_bytes ? offA : wout_bytes);
  off = (off + 255) & ~(size_t)255;
  auto alloc = [&](size_t b) {
    char* p = ws + off;
    off = (off + b + 255) & ~(size_t)255;
    return p;
  };

  u16* hs = (u16*)alloc((size_t)MP * HH * 2);
  float* h0f = (float*)alloc((size_t)2 * BB * HH * 4);
  float* h1f = (float*)alloc((size_t)2 * BB * HH * 4);
  f16* h0x = (f16*)alloc((size_t)2 * BB * HH * 2);
  f16* h1x = (f16*)alloc((size_t)2 * BB * HH * 2);
  float* tok = (float*)alloc((size_t)MM * 4);
  u32* bar = (u32*)alloc((size_t)64 * 16 * 4);

  hipMemsetAsync(h0f, 0, (size_t)2 * BB * HH * 4, stream);
  hipMemsetAsync(h1f, 0, (size_t)2 * BB * HH * 4, stream);
  hipMemsetAsync(h0x, 0, (size_t)2 * BB * HH * 2, stream);
  hipMemsetAsync(h1x, 0, (size_t)2 * BB * HH * 2, stream);
  hipMemsetAsync(hs, 0, (size_t)MP * HH * 2, stream);
  hipMemsetAsync(bar, 0, (size_t)64 * 16 * 4, stream);
  hipMemsetAsync(xh + (size_t)MM * EP, 0, (size_t)(MP - MM) * EP * 2, stream);
  hipMemsetAsync(xl + (size_t)MM * EP, 0, (size_t)(MP - MM) * EP * 2, stream);

  cvt_f16<<<1024, 256, 0, stream>>>(Wh0, wh0f, H3 * HH / 4);
  cvt_f16<<<1024, 256, 0, stream>>>(Wi1, wi1f, H3 * HH / 4);
  cvt_f16<<<1024, 256, 0, stream>>>(Wh1, wh1f, H3 * HH / 4);
  cvt_wi0_split<<<512, 256, 0, stream>>>(Wi0, wi0h, wi0l);
  gather_x_split<<<512, 256, 0, stream>>>(sent, emb, xh, xl);

  gemm_bt<false, true><<<16 * 24, 256, 0, stream>>>(xh, xl, EP, wi0h, wi0l, bi0, gx0, H3,
                                                    5, 16, MM);

  RecArgs ra{wh0f, wi1f, wh1f, gx0, bh0, bi1, bh1, h0f, h1f, h0x, h1x, hs, bar};
  void* kargs[] = {(void*)&ra};
  hipLaunchCooperativeKernel((void*)rec_kernel, dim3(NWG), dim3(256), kargs, 0, stream);

  // Wout conversion AFTER rec: woutb aliases the (now dead) recurrence weights.
  cvt_bf16<<<2048, 256, 0, stream>>>(Wout, woutb, VV * HH / 4);

  gemm_bt<true, false><<<16 * 250, 256, 0, stream>>>(hs, nullptr, HH, woutb, nullptr, bout,
                                                     out + 1, VV, 16, 16, MM);

  rowred_kernel<<<MM, 256, 0, stream>>>(out + 1, sent, length, tok);
  loss_kernel<<<1, 64, 0, stream>>>(tok, length, out);
}

// Round 9
// 1252.382 us; speedup vs baseline: 2.9410x; 1.2597x over previous
//
#include <hip/hip_runtime.h>

typedef unsigned short u16;
typedef unsigned int u32;
typedef unsigned long long u64;
typedef _Float16 f16;
typedef __attribute__((ext_vector_type(8))) __bf16 bf16x8;
typedef __attribute__((ext_vector_type(8))) _Float16 f16x8;
typedef __attribute__((ext_vector_type(4))) _Float16 f16x4;
typedef __attribute__((ext_vector_type(4))) float f32x4;

#define DEVI static __device__ __forceinline__

#define BB 32
#define SS 64
#define TT 63
#define VV 32000
#define EE 300
#define EP 320
#define HH 1024
#define H3 3072
#define MM 2016
#define MP 2048
#define NWG 192

DEVI u16 f2bf(float f) {
  u32 x = __float_as_uint(f);
  u32 r = x + 0x7FFFu + ((x >> 16) & 1u);
  return (u16)(r >> 16);
}
DEVI float bf2f(u16 h) { return __uint_as_float(((u32)h) << 16); }
DEVI void split2(float x, u16& hi, u16& lo) {
  hi = f2bf(x);
  lo = f2bf(x - bf2f(hi));
}
DEVI float sigm(float x) { return 1.0f / (1.0f + __expf(-x)); }
DEVI float tanh_(float x) { return 2.0f / (1.0f + __expf(-2.0f * x)) - 1.0f; }

DEVI void gl_lds16(const void* g, void* l) {
  __builtin_amdgcn_global_load_lds((const __attribute__((address_space(1))) void*)g,
                                   (__attribute__((address_space(3))) void*)l,
                                   16, 0, 0);
}

DEVI f32x4 mfma_bf16(bf16x8 a, bf16x8 b, f32x4 c) {
  return __builtin_amdgcn_mfma_f32_16x16x32_bf16(a, b, c, 0, 0, 0);
}
DEVI f32x4 mfma_f16(f16x8 a, f16x8 b, f32x4 c) {
  return __builtin_amdgcn_mfma_f32_16x16x32_f16(a, b, c, 0, 0, 0);
}

// Device-scope (IF$-coherent) h-state exchange, fragment-major layout:
// h buffer = [c4 = j>>2][b (0..31)][4 x f16]  (8B granule per (c4,b)).
// Reader (A-fragment for mfma 16x16x32): lane needs j-chunks c4 = kk*8+kg*2
// and +1 for batch row `brow` -> two u64 loads, lanes 0..15 contiguous 128B.
DEVI f16x8 frag_ld(const f16* base, int kk, int kg, int brow) {
  const u64* q = (const u64*)base;
  int i0 = (kk * 8 + kg * 2) * 32 + brow;
  union { u64 u[2]; f16x8 v; } t;
  t.u[0] = __hip_atomic_load(q + i0, __ATOMIC_RELAXED, __HIP_MEMORY_SCOPE_AGENT);
  t.u[1] = __hip_atomic_load(q + i0 + 32, __ATOMIC_RELAXED, __HIP_MEMORY_SCOPE_AGENT);
  return t.v;
}
DEVI void ast32(u32* p, u32 v) {
  __hip_atomic_store(p, v, __ATOMIC_RELAXED, __HIP_MEMORY_SCOPE_AGENT);
}
// Writer slot for (col j0 even, batch b): bytes (j0>>2)*256 + b*8 + (j0&3)*2.
DEVI u32* frag_wslot(f16* base, int j0, int b) {
  return (u32*)((char*)base + ((j0 >> 2) * 256 + b * 8 + (j0 & 3) * 2));
}

// Cache-neutral grid barrier (all cross-WG data at IF$ via sc1 ops).
DEVI void gbar(u32* bar, int idx) {
  __syncthreads();
  if (threadIdx.x == 0) {
    u32* c = bar + idx * 16;
    __hip_atomic_fetch_add(c, 1u, __ATOMIC_RELAXED, __HIP_MEMORY_SCOPE_AGENT);
    while (__hip_atomic_load(c, __ATOMIC_RELAXED, __HIP_MEMORY_SCOPE_AGENT) < NWG)
      __builtin_amdgcn_s_sleep(1);
  }
  __syncthreads();
}

// ---------------- converts / gather ----------------

__global__ void cvt_bf16(const float* __restrict__ in, u16* __restrict__ out, int n4) {
  int i = blockIdx.x * 256 + threadIdx.x;
  int stride = gridDim.x * 256;
  for (; i < n4; i += stride) {
    float4 v = ((const float4*)in)[i];
    ushort4 o;
    o.x = f2bf(v.x); o.y = f2bf(v.y); o.z = f2bf(v.z); o.w = f2bf(v.w);
    ((ushort4*)out)[i] = o;
  }
}

__global__ void cvt_f16(const float* __restrict__ in, f16* __restrict__ out, int n4) {
  int i = blockIdx.x * 256 + threadIdx.x;
  int stride = gridDim.x * 256;
  for (; i < n4; i += stride) {
    float4 v = ((const float4*)in)[i];
    f16x4 o = {(f16)v.x, (f16)v.y, (f16)v.z, (f16)v.w};
    ((f16x4*)out)[i] = o;
  }
}

__global__ void cvt_split(const float* __restrict__ in, u16* __restrict__ hi,
                          u16* __restrict__ lo, int n4) {
  int i = blockIdx.x * 256 + threadIdx.x;
  int stride = gridDim.x * 256;
  for (; i < n4; i += stride) {
    float4 v = ((const float4*)in)[i];
    ushort4 h, l;
    split2(v.x, h.x, l.x);
    split2(v.y, h.y, l.y);
    split2(v.z, h.z, l.z);
    split2(v.w, h.w, l.w);
    ((ushort4*)hi)[i] = h;
    ((ushort4*)lo)[i] = l;
  }
}

__global__ void cvt_wi0_split(const float* __restrict__ W, u16* __restrict__ hi,
                              u16* __restrict__ lo) {
  int i = blockIdx.x * 256 + threadIdx.x;
  int stride = gridDim.x * 256;
  for (; i < H3 * EP; i += stride) {
    int r = i / EP, c = i % EP;
    u16 h = 0, l = 0;
    if (c < EE) split2(W[(size_t)r * EE + c], h, l);
    hi[i] = h;
    lo[i] = l;
  }
}

__global__ void gather_x_split(const int* __restrict__ sent, const float* __restrict__ emb,
                               u16* __restrict__ xh, u16* __restrict__ xl) {
  int i = blockIdx.x * 256 + threadIdx.x;
  int stride = gridDim.x * 256;
  for (; i < MM * EP; i += stride) {
    int m = i / EP, c = i % EP;
    int t = m >> 5, b = m & 31;
    int tok = sent[b * SS + t];
    u16 h = 0, l = 0;
    if (c < EE) split2(emb[(size_t)tok * EE + c], h, l);
    xh[i] = h;
    xl[i] = l;
  }
}

// ---------------- GEMM: C[m][n] = A[m][:] . B[n][:] + bias[n] (bf16) --------

template <bool REMAP, bool SPLIT>
__global__ __launch_bounds__(256) void gemm_bt(const u16* __restrict__ Ah,
                                               const u16* __restrict__ Al, int lda,
                                               const u16* __restrict__ Bh,
                                               const u16* __restrict__ Bl,
                                               const float* __restrict__ bias,
                                               float* __restrict__ out, int out_stride,
                                               int Ksteps, int Mtiles, int Mvalid) {
  __shared__ u16 As[(SPLIT ? 2 : 1) * 128 * 64];
  __shared__ u16 Bs[(SPLIT ? 2 : 1) * 128 * 64];
  const int bid = blockIdx.x;
  const int mtile = bid % Mtiles, ntile = bid / Mtiles;
  const int tid = threadIdx.x;
  const int lane = tid & 63, wave = tid >> 6;
  const int wrow = (wave & 1) * 64, wcol = (wave >> 1) * 64;
  const int l15 = lane & 15, kg = lane >> 4;

  f32x4 acc[4][4];
#pragma unroll
  for (int i = 0; i < 4; ++i)
#pragma unroll
    for (int j = 0; j < 4; ++j) {
      f32x4 z = {0.f, 0.f, 0.f, 0.f};
      acc[i][j] = z;
    }

  for (int ks = 0; ks < Ksteps; ++ks) {
    int k0 = ks * 64;
#pragma unroll
    for (int it = 0; it < 4; ++it) {
      int c = it * 256 + tid;
      int r = c >> 3, kc = (c & 7) * 8;
      gl_lds16(Ah + (size_t)(mtile * 128 + r) * lda + k0 + kc, &As[c * 8]);
      gl_lds16(Bh + (size_t)(ntile * 128 + r) * lda + k0 + kc, &Bs[c * 8]);
      if constexpr (SPLIT) {
        gl_lds16(Al + (size_t)(mtile * 128 + r) * lda + k0 + kc, &As[8192 + c * 8]);
        gl_lds16(Bl + (size_t)(ntile * 128 + r) * lda + k0 + kc, &Bs[8192 + c * 8]);
      }
    }
    __syncthreads();
#pragma unroll
    for (int kk = 0; kk < 2; ++kk) {
      bf16x8 ah[4], bh[4], al[4], bl[4];
#pragma unroll
      for (int i = 0; i < 4; ++i) {
        int ao = (wrow + i * 16 + l15) * 64 + kk * 32 + kg * 8;
        int bo = (wcol + i * 16 + l15) * 64 + kk * 32 + kg * 8;
        ah[i] = *(const bf16x8*)&As[ao];
        bh[i] = *(const bf16x8*)&Bs[bo];
        if constexpr (SPLIT) {
          al[i] = *(const bf16x8*)&As[8192 + ao];
          bl[i] = *(const bf16x8*)&Bs[8192 + bo];
        }
      }
#pragma unroll
      for (int i = 0; i < 4; ++i)
#pragma unroll
        for (int j = 0; j < 4; ++j) {
          f32x4 t = mfma_bf16(ah[i], bh[j], acc[i][j]);
          if constexpr (SPLIT) {
            t = mfma_bf16(ah[i], bl[j], t);
            t = mfma_bf16(al[i], bh[j], t);
          }
          acc[i][j] = t;
        }
    }
    __syncthreads();
  }

  const int r0 = kg * 4;
#pragma unroll
  for (int i = 0; i < 4; ++i) {
    int mbase = mtile * 128 + wrow + i * 16 + r0;
#pragma unroll
    for (int j = 0; j < 4; ++j) {
      int n = ntile * 128 + wcol + j * 16 + l15;
      float bv = bias[n];
#pragma unroll
      for (int reg = 0; reg < 4; ++reg) {
        int m = mbase + reg;
        if (m < Mvalid) {
          float v = acc[i][j][reg] + bv;
          size_t oidx;
          if (REMAP) {
            int b = m & 31, s = m >> 5;
            oidx = ((size_t)(b * TT + s)) * VV + n;
          } else {
            oidx = (size_t)m * out_stride + n;
          }
          out[oidx] = v;
        }
      }
    }
  }
}

// ---------------- recurrence (192 WGs, 64 phases, custom IF$ barrier) -------
// Weights LDS-resident. h-exchange via sc1 atomics in fragment-major layout
// (coalesced IF$ lines). Per-thread fp32 h_prev kept in registers.
// L0: WGs 0..63, 16 cols each. LDS rows: [r:0-15][z:16-31][n:32-47].
// L1: WGs 64..191, 8 cols each. LDS rows: [gi_r:0-7][gi_z:8-15][gi_n:16-23]
//     [gh_r:24-31][gh_z:32-39][gh_n:40-47]; B-tiles read rows via l15&7.
// Weight LDS XOR swizzle (both sides): byte ^= (row&7)<<4 within each 2KB row.

struct RecArgs {
  const f16 *wh0, *wi1, *wh1;
  const float *gx0, *bh0, *bi1, *bh1;
  f16 *h0x, *h1x;  // fragment-major exchange buffers, [2][BB*HH] f16
  u16 *hs;
  u32 *bar;
};

__global__ __launch_bounds__(256, 1) void rec_kernel(RecArgs ra) {
  __shared__ f16 wlds[48 * 1024];
  __shared__ float gh[48 * 33];
  const int tid = threadIdx.x;
  const int lane = tid & 63, wave = tid >> 6;
  const int wg = blockIdx.x;
  const bool isL0 = wg < 64;
  const int Jbase = isL0 ? (wg * 16) : ((wg - 64) * 8);
  const int l15 = lane & 15;
  const int kg = lane >> 4;
  const int swz = (l15 & 7) << 4;
  char* wb = (char*)wlds;

  // ---- prologue: stage this WG's weight slice into LDS (swizzled) ----
#pragma unroll
  for (int it = 0; it < 24; ++it) {
    int q = it * 256 + tid;  // 0..6143
    int r = q >> 7;          // LDS row 0..47
    int c16 = q & 127;       // 16B chunk within row
    const f16* gp;
    if (isL0) {
      int gate = r >> 4, colr = r & 15;
      gp = ra.wh0 + ((size_t)(gate * HH + Jbase + colr)) * HH + c16 * 8;
    } else {
      int tile = r >> 3, colr = r & 7;
      int msrc = tile / 3, gate = tile - msrc * 3;
      const f16* W = msrc ? ra.wh1 : ra.wi1;
      gp = W + ((size_t)(gate * HH + Jbase + colr)) * HH + c16 * 8;
    }
    f16x8 v = *(const f16x8*)gp;
    int byte = r * 2048 + ((c16 * 16) ^ ((r & 7) << 4));
    *(f16x8*)(wb + byte) = v;
  }

  // ---- per-thread EW state: registers (bias preload, h_prev) ----
  const int ewb = tid & 31, ewjp = tid >> 5;
  float hprev[2] = {0.f, 0.f};
  float pb0r[2], pb0z[2], pb0n[2];                 // L0 biases
  float pbrz_r[2], pbrz_z[2], pbn_i[2], pbn_h[2];  // L1 biases
  if (isL0) {
    const int j0 = ewjp * 2;
#pragma unroll
    for (int s = 0; s < 2; ++s) {
      int gj = Jbase + j0 + s;
      pb0r[s] = ra.bh0[gj];
      pb0z[s] = ra.bh0[HH + gj];
      pb0n[s] = ra.bh0[2 * HH + gj];
    }
  } else if (tid < 128) {
    const int j0 = ewjp * 2;
#pragma unroll
    for (int s = 0; s < 2; ++s) {
      int gj = Jbase + j0 + s;
      pbrz_r[s] = ra.bi1[gj] + ra.bh1[gj];
      pbrz_z[s] = ra.bi1[HH + gj] + ra.bh1[HH + gj];
      pbn_i[s] = ra.bi1[2 * HH + gj];
      pbn_h[s] = ra.bh1[2 * HH + gj];
    }
  }
  __syncthreads();

  for (int p = 0; p < 64; ++p) {
    const int pb = p & 1, qb = (p + 1) & 1;
    if (isL0) {
      if (p < TT) {
        // prefetch gx for this thread's EW (hides HBM latency under MFMA)
        float gr[2], gz[2], gn[2];
        {
          const float* gxb = ra.gx0 + ((size_t)p * BB + ewb) * H3;
          const int j0 = ewjp * 2;
#pragma unroll
          for (int s = 0; s < 2; ++s) {
            int gj = Jbase + j0 + s;
            gr[s] = gxb[gj];
            gz[s] = gxb[HH + gj];
            gn[s] = gxb[2 * HH + gj];
          }
        }
        const int rt = wave >> 1, tt = wave & 1;
        const f16* h0base = ra.h0x + (size_t)qb * (BB * HH);
        const int brow = rt * 16 + l15;
        f32x4 z = {0.f, 0.f, 0.f, 0.f};
        if (tt == 0) {
          f32x4 acc0 = z, acc1 = z;
#pragma unroll 4
          for (int kk = 0; kk < 32; ++kk) {
            f16x8 a = frag_ld(h0base, kk, kg, brow);
            int inner = (kk * 64 + kg * 16) ^ swz;
            f16x8 b0 = *(const f16x8*)(wb + (0 * 16 + l15) * 2048 + inner);
            f16x8 b1 = *(const f16x8*)(wb + (1 * 16 + l15) * 2048 + inner);
            acc0 = mfma_f16(a, b0, acc0);
            acc1 = mfma_f16(a, b1, acc1);
          }
#pragma unroll
          for (int r = 0; r < 4; ++r) {
            gh[(l15)*33 + rt * 16 + kg * 4 + r] = acc0[r];
            gh[(16 + l15) * 33 + rt * 16 + kg * 4 + r] = acc1[r];
          }
        } else {
          f32x4 acc2 = z;
#pragma unroll 4
          for (int kk = 0; kk < 32; ++kk) {
            f16x8 a = frag_ld(h0base, kk, kg, brow);
            int inner = (kk * 64 + kg * 16) ^ swz;
            f16x8 b2 = *(const f16x8*)(wb + (2 * 16 + l15) * 2048 + inner);
            acc2 = mfma_f16(a, b2, acc2);
          }
#pragma unroll
          for (int r = 0; r < 4; ++r)
            gh[(32 + l15) * 33 + rt * 16 + kg * 4 + r] = acc2[r];
        }
        __syncthreads();
        // elementwise
        f16* hxc = ra.h0x + (size_t)pb * (BB * HH);
        const int j0 = ewjp * 2;
        float hn2[2];
#pragma unroll
        for (int s = 0; s < 2; ++s) {
          int j = j0 + s;
          float rh = gh[(j)*33 + ewb] + pb0r[s];
          float zh = gh[(16 + j) * 33 + ewb] + pb0z[s];
          float nh = gh[(32 + j) * 33 + ewb] + pb0n[s];
          float r = sigm(gr[s] + rh);
          float zz = sigm(gz[s] + zh);
          float n = tanh_(gn[s] + r * nh);
          hn2[s] = (1.f - zz) * n + zz * hprev[s];
          hprev[s] = hn2[s];
        }
        union { f16 h[2]; u32 u; } pk;
        pk.h[0] = (f16)hn2[0];
        pk.h[1] = (f16)hn2[1];
        ast32(frag_wslot(hxc, Jbase + j0, ewb), pk.u);
      } else {
        __syncthreads();
      }
    } else {
      if (p >= 1) {
        const int rt = wave >> 1, src = wave & 1;
        const f16* hbase = (src ? ra.h1x : ra.h0x) + (size_t)qb * (BB * HH);
        const int brow = rt * 16 + l15;
        const int rowb = src * 24 + (l15 & 7);
        f32x4 z = {0.f, 0.f, 0.f, 0.f};
        f32x4 acc0 = z, acc1 = z, acc2 = z;
#pragma unroll 4
        for (int kk = 0; kk < 32; ++kk) {
          f16x8 a = frag_ld(hbase, kk, kg, brow);
          int inner = (kk * 64 + kg * 16) ^ swz;
          f16x8 b0 = *(const f16x8*)(wb + (rowb + 0) * 2048 + inner);
          f16x8 b1 = *(const f16x8*)(wb + (rowb + 8) * 2048 + inner);
          f16x8 b2 = *(const f16x8*)(wb + (rowb + 16) * 2048 + inner);
          acc0 = mfma_f16(a, b0, acc0);
          acc1 = mfma_f16(a, b1, acc1);
          acc2 = mfma_f16(a, b2, acc2);
        }
        if (l15 < 8) {
          f32x4 accs[3] = {acc0, acc1, acc2};
#pragma unroll
          for (int g = 0; g < 3; ++g) {
            int cl = (src * 3 + g) * 8 + l15;
#pragma unroll
            for (int r = 0; r < 4; ++r)
              gh[cl * 33 + rt * 16 + kg * 4 + r] = accs[g][r];
          }
        }
        __syncthreads();
        if (tid < 128) {
          f16* hxc = ra.h1x + (size_t)pb * (BB * HH);
          const int j0 = ewjp * 2;
          float hn2[2];
#pragma unroll
          for (int s = 0; s < 2; ++s) {
            int j = j0 + s;
            // FIX: six-row gh layout — sum gi and gh parts per gate.
            float gir = gh[(j)*33 + ewb];
            float giz = gh[(8 + j) * 33 + ewb];
            float gin = gh[(16 + j) * 33 + ewb];
            float ghr = gh[(24 + j) * 33 + ewb];
            float ghz = gh[(32 + j) * 33 + ewb];
            float ghn = gh[(40 + j) * 33 + ewb];
            float r = sigm(gir + ghr + pbrz_r[s]);
            float zz = sigm(giz + ghz + pbrz_z[s]);
            float n = tanh_(gin + pbn_i[s] + r * (ghn + pbn_h[s]));
            hn2[s] = (1.f - zz) * n + zz * hprev[s];
            hprev[s] = hn2[s];
          }
          union { f16 h[2]; u32 u; } pk;
          pk.h[0] = (f16)hn2[0];
          pk.h[1] = (f16)hn2[1];
          ast32(frag_wslot(hxc, Jbase + j0, ewb), pk.u);
          union { u16 h[2]; u32 u; } pb2;
          pb2.h[0] = f2bf(hn2[0]);
          pb2.h[1] = f2bf(hn2[1]);
          *(u32*)&ra.hs[((size_t)(p - 1) * BB + ewb) * HH + Jbase + j0] = pb2.u;
        }
      } else {
        __syncthreads();
      }
    }
    if (p < 63) gbar(ra.bar, p);
  }
}

// ---------------- row reductions + loss ----------------

__global__ __launch_bounds__(256) void rowred_kernel(const float* __restrict__ logits,
                                                     const int* __restrict__ sent,
                                                     const int* __restrict__ length,
                                                     float* __restrict__ tok) {
  __shared__ float red[8];
  const int row = blockIdx.x;  // b*63 + s
  const int b = row / TT, s = row % TT;
  const float* p = logits + (size_t)row * VV;
  const int tid = threadIdx.x;

  float m = -1e30f;
  for (int i = tid; i < VV; i += 256) m = fmaxf(m, p[i]);
  for (int off = 1; off < 64; off <<= 1) m = fmaxf(m, __shfl_xor(m, off));
  if ((tid & 63) == 0) red[tid >> 6] = m;
  __syncthreads();
  m = fmaxf(fmaxf(red[0], red[1]), fmaxf(red[2], red[3]));

  float sum = 0.f;
  for (int i = tid; i < VV; i += 256) sum += __expf(p[i] - m);
  for (int off = 1; off < 64; off <<= 1) sum += __shfl_xor(sum, off);
  if ((tid & 63) == 0) red[4 + (tid >> 6)] = sum;
  __syncthreads();
  if (tid == 0) {
    float tot = red[4] + red[5] + red[6] + red[7];
    float lse = m + __logf(tot);
    int tgt = sent[b * SS + s + 1];
    float tl = p[tgt] - lse;
    if (s >= length[b] - 1) tl = 0.f;
    tok[row] = tl;
  }
}

__global__ void loss_kernel(const float* __restrict__ tok, const int* __restrict__ length,
                            float* __restrict__ out0) {
  int lane = threadIdx.x;
  float v = 0.f;
  if (lane < BB) {
    float s = 0.f;
    for (int t = 0; t < TT; ++t) s += tok[lane * TT + t];
    float ln = (float)(length[lane] - 1);
    v = -s / ln;
  }
  v += __shfl_down(v, 16);
  v += __shfl_down(v, 8);
  v += __shfl_down(v, 4);
  v += __shfl_down(v, 2);
  v += __shfl_down(v, 1);
  if (lane == 0) out0[0] = v / (float)BB;
}

// ---------------- host ----------------

extern "C" void kernel_launch(void* const* d_in, const int* in_sizes, int n_in,
                              void* d_out, int out_size, void* d_ws, size_t ws_size,
                              hipStream_t stream) {
  const int* sent = (const int*)d_in[0];
  const int* length = (const int*)d_in[1];
  const float* emb = (const float*)d_in[2];
  const float* Wi0 = (const float*)d_in[3];
  const float* Wh0 = (const float*)d_in[4];
  const float* bi0 = (const float*)d_in[5];
  const float* bh0 = (const float*)d_in[6];
  const float* Wi1 = (const float*)d_in[7];
  const float* Wh1 = (const float*)d_in[8];
  const float* bi1 = (const float*)d_in[9];
  const float* bh1 = (const float*)d_in[10];
  const float* Wout = (const float*)d_in[11];
  const float* bout = (const float*)d_in[12];
  float* out = (float*)d_out;

  char* ws = (char*)d_ws;
  // Region A: recurrence-phase-only buffers; woutb aliases it after rec.
  size_t offA = 0;
  auto allocA = [&](size_t b) {
    char* p = ws + offA;
    offA = (offA + b + 255) & ~(size_t)255;
    return p;
  };
  f16* wh0f = (f16*)allocA((size_t)H3 * HH * 2);
  f16* wi1f = (f16*)allocA((size_t)H3 * HH * 2);
  f16* wh1f = (f16*)allocA((size_t)H3 * HH * 2);
  u16* wi0h = (u16*)allocA((size_t)H3 * EP * 2);
  u16* wi0l = (u16*)allocA((size_t)H3 * EP * 2);
  u16* xh = (u16*)allocA((size_t)MP * EP * 2);
  u16* xl = (u16*)allocA((size_t)MP * EP * 2);
  float* gx0 = (float*)allocA((size_t)MM * H3 * 4);
  u16* woutb = (u16*)ws;  // alias over region A, used after rec
  size_t wout_bytes = (size_t)VV * HH * 2;
  size_t off = (offA > wout_bytes ? offA : wout_bytes);
  off = (off + 255) & ~(size_t)255;
  auto alloc = [&](size_t b) {
    char* p = ws + off;
    off = (off + b + 255) & ~(size_t)255;
    return p;
  };

  u16* hs = (u16*)alloc((size_t)MP * HH * 2);
  f16* h0x = (f16*)alloc((size_t)2 * BB * HH * 2);
  f16* h1x = (f16*)alloc((size_t)2 * BB * HH * 2);
  float* tok = (float*)alloc((size_t)MM * 4);
  u32* bar = (u32*)alloc((size_t)64 * 16 * 4);

  hipMemsetAsync(h0x, 0, (size_t)2 * BB * HH * 2, stream);
  hipMemsetAsync(h1x, 0, (size_t)2 * BB * HH * 2, stream);
  hipMemsetAsync(hs, 0, (size_t)MP * HH * 2, stream);
  hipMemsetAsync(bar, 0, (size_t)64 * 16 * 4, stream);
  hipMemsetAsync(xh + (size_t)MM * EP, 0, (size_t)(MP - MM) * EP * 2, stream);
  hipMemsetAsync(xl + (size_t)MM * EP, 0, (size_t)(MP - MM) * EP * 2, stream);

  cvt_f16<<<1024, 256, 0, stream>>>(Wh0, wh0f, H3 * HH / 4);
  cvt_f16<<<1024, 256, 0, stream>>>(Wi1, wi1f, H3 * HH / 4);
  cvt_f16<<<1024, 256, 0, stream>>>(Wh1, wh1f, H3 * HH / 4);
  cvt_wi0_split<<<512, 256, 0, stream>>>(Wi0, wi0h, wi0l);
  gather_x_split<<<512, 256, 0, stream>>>(sent, emb, xh, xl);

  gemm_bt<false, true><<<16 * 24, 256, 0, stream>>>(xh, xl, EP, wi0h, wi0l, bi0, gx0, H3,
                                                    5, 16, MM);

  RecArgs ra{wh0f, wi1f, wh1f, gx0, bh0, bi1, bh1, h0x, h1x, hs, bar};
  void* kargs[] = {(void*)&ra};
  hipLaunchCooperativeKernel((void*)rec_kernel, dim3(NWG), dim3(256), kargs, 0, stream);

  // Wout conversion AFTER rec: woutb aliases the (now dead) recurrence weights.
  cvt_bf16<<<2048, 256, 0, stream>>>(Wout, woutb, VV * HH / 4);

  gemm_bt<true, false><<<16 * 250, 256, 0, stream>>>(hs, nullptr, HH, woutb, nullptr, bout,
                                                     out + 1, VV, 16, 16, MM);

  rowred_kernel<<<MM, 256, 0, stream>>>(out + 1, sent, length, tok);
  loss_kernel<<<1, 64, 0, stream>>>(tok, length, out);
}

// Round 10
// 1051.327 us; speedup vs baseline: 3.5035x; 1.1912x over previous
//
#include <hip/hip_runtime.h>

typedef unsigned short u16;
typedef unsigned int u32;
typedef unsigned long long u64;
typedef _Float16 f16;
typedef __attribute__((ext_vector_type(8))) __bf16 bf16x8;
typedef __attribute__((ext_vector_type(8))) _Float16 f16x8;
typedef __attribute__((ext_vector_type(4))) _Float16 f16x4;
typedef __attribute__((ext_vector_type(4))) float f32x4;

#define DEVI static __device__ __forceinline__

#define BB 32
#define SS 64
#define TT 63
#define VV 32000
#define EE 300
#define EP 320
#define HH 1024
#define H3 3072
#define MM 2016
#define MP 2048
#define NWG 192

DEVI u16 f2bf(float f) {
  u32 x = __float_as_uint(f);
  u32 r = x + 0x7FFFu + ((x >> 16) & 1u);
  return (u16)(r >> 16);
}
DEVI float bf2f(u16 h) { return __uint_as_float(((u32)h) << 16); }
DEVI void split2(float x, u16& hi, u16& lo) {
  hi = f2bf(x);
  lo = f2bf(x - bf2f(hi));
}
DEVI float sigm(float x) { return 1.0f / (1.0f + __expf(-x)); }
DEVI float tanh_(float x) { return 2.0f / (1.0f + __expf(-2.0f * x)) - 1.0f; }

DEVI void gl_lds16(const void* g, void* l) {
  __builtin_amdgcn_global_load_lds((const __attribute__((address_space(1))) void*)g,
                                   (__attribute__((address_space(3))) void*)l,
                                   16, 0, 0);
}

DEVI f32x4 mfma_bf16(bf16x8 a, bf16x8 b, f32x4 c) {
  return __builtin_amdgcn_mfma_f32_16x16x32_bf16(a, b, c, 0, 0, 0);
}
DEVI f32x4 mfma_f16(f16x8 a, f16x8 b, f32x4 c) {
  return __builtin_amdgcn_mfma_f32_16x16x32_f16(a, b, c, 0, 0, 0);
}

// Device-scope (IF$-coherent) h-state exchange, fragment-major layout:
// h buffer = [c4 = j>>2][b (0..31)][4 x f16]  (8B granule per (c4,b)).
DEVI f16x8 frag_ld(const f16* base, int kk, int kg, int brow) {
  const u64* q = (const u64*)base;
  int i0 = (kk * 8 + kg * 2) * 32 + brow;
  union { u64 u[2]; f16x8 v; } t;
  t.u[0] = __hip_atomic_load(q + i0, __ATOMIC_RELAXED, __HIP_MEMORY_SCOPE_AGENT);
  t.u[1] = __hip_atomic_load(q + i0 + 32, __ATOMIC_RELAXED, __HIP_MEMORY_SCOPE_AGENT);
  return t.v;
}
DEVI void ast32(u32* p, u32 v) {
  __hip_atomic_store(p, v, __ATOMIC_RELAXED, __HIP_MEMORY_SCOPE_AGENT);
}
DEVI u32 ald32(const u32* p) {
  return __hip_atomic_load(p, __ATOMIC_RELAXED, __HIP_MEMORY_SCOPE_AGENT);
}
// Writer slot for (col j0 even, batch b): bytes (j0>>2)*256 + b*8 + (j0&3)*2.
DEVI u32* frag_wslot(f16* base, int j0, int b) {
  return (u32*)((char*)base + ((j0 >> 2) * 256 + b * 8 + (j0 & 3) * 2));
}

// Distributed-flag grid barrier: no RMW, no shared-line contention.
// Each WG owns one 64B flag line; arrival = one sc1 store; detection =
// 192 parallel sc1 loads (one per thread) + __syncthreads_and.
// The leading __syncthreads drains vmcnt -> this WG's sc1 h-stores are
// ACKed at the IF$ coherence point before the flag store issues.
DEVI void gbar(u32* flags, int wg, u32 target) {
  __syncthreads();
  if (threadIdx.x == 0) ast32(&flags[wg * 16], target);
  int ok;
  do {
    u32 v = (threadIdx.x < NWG) ? ald32(&flags[threadIdx.x * 16]) : target;
    ok = (v >= target);
  } while (__syncthreads_and(ok) == 0);
}

// ---------------- converts / gather ----------------

__global__ void cvt_bf16(const float* __restrict__ in, u16* __restrict__ out, int n4) {
  int i = blockIdx.x * 256 + threadIdx.x;
  int stride = gridDim.x * 256;
  for (; i < n4; i += stride) {
    float4 v = ((const float4*)in)[i];
    ushort4 o;
    o.x = f2bf(v.x); o.y = f2bf(v.y); o.z = f2bf(v.z); o.w = f2bf(v.w);
    ((ushort4*)out)[i] = o;
  }
}

__global__ void cvt_f16(const float* __restrict__ in, f16* __restrict__ out, int n4) {
  int i = blockIdx.x * 256 + threadIdx.x;
  int stride = gridDim.x * 256;
  for (; i < n4; i += stride) {
    float4 v = ((const float4*)in)[i];
    f16x4 o = {(f16)v.x, (f16)v.y, (f16)v.z, (f16)v.w};
    ((f16x4*)out)[i] = o;
  }
}

__global__ void cvt_split(const float* __restrict__ in, u16* __restrict__ hi,
                          u16* __restrict__ lo, int n4) {
  int i = blockIdx.x * 256 + threadIdx.x;
  int stride = gridDim.x * 256;
  for (; i < n4; i += stride) {
    float4 v = ((const float4*)in)[i];
    ushort4 h, l;
    split2(v.x, h.x, l.x);
    split2(v.y, h.y, l.y);
    split2(v.z, h.z, l.z);
    split2(v.w, h.w, l.w);
    ((ushort4*)hi)[i] = h;
    ((ushort4*)lo)[i] = l;
  }
}

__global__ void cvt_wi0_split(const float* __restrict__ W, u16* __restrict__ hi,
                              u16* __restrict__ lo) {
  int i = blockIdx.x * 256 + threadIdx.x;
  int stride = gridDim.x * 256;
  for (; i < H3 * EP; i += stride) {
    int r = i / EP, c = i % EP;
    u16 h = 0, l = 0;
    if (c < EE) split2(W[(size_t)r * EE + c], h, l);
    hi[i] = h;
    lo[i] = l;
  }
}

__global__ void gather_x_split(const int* __restrict__ sent, const float* __restrict__ emb,
                               u16* __restrict__ xh, u16* __restrict__ xl) {
  int i = blockIdx.x * 256 + threadIdx.x;
  int stride = gridDim.x * 256;
  for (; i < MM * EP; i += stride) {
    int m = i / EP, c = i % EP;
    int t = m >> 5, b = m & 31;
    int tok = sent[b * SS + t];
    u16 h = 0, l = 0;
    if (c < EE) split2(emb[(size_t)tok * EE + c], h, l);
    xh[i] = h;
    xl[i] = l;
  }
}

// ---------------- GEMM: C[m][n] = A[m][:] . B[n][:] + bias[n] (bf16) --------

template <bool REMAP, bool SPLIT>
__global__ __launch_bounds__(256) void gemm_bt(const u16* __restrict__ Ah,
                                               const u16* __restrict__ Al, int lda,
                                               const u16* __restrict__ Bh,
                                               const u16* __restrict__ Bl,
                                               const float* __restrict__ bias,
                                               float* __restrict__ out, int out_stride,
                                               int Ksteps, int Mtiles, int Mvalid) {
  __shared__ u16 As[(SPLIT ? 2 : 1) * 128 * 64];
  __shared__ u16 Bs[(SPLIT ? 2 : 1) * 128 * 64];
  const int bid = blockIdx.x;
  const int mtile = bid % Mtiles, ntile = bid / Mtiles;
  const int tid = threadIdx.x;
  const int lane = tid & 63, wave = tid >> 6;
  const int wrow = (wave & 1) * 64, wcol = (wave >> 1) * 64;
  const int l15 = lane & 15, kg = lane >> 4;

  f32x4 acc[4][4];
#pragma unroll
  for (int i = 0; i < 4; ++i)
#pragma unroll
    for (int j = 0; j < 4; ++j) {
      f32x4 z = {0.f, 0.f, 0.f, 0.f};
      acc[i][j] = z;
    }

  for (int ks = 0; ks < Ksteps; ++ks) {
    int k0 = ks * 64;
#pragma unroll
    for (int it = 0; it < 4; ++it) {
      int c = it * 256 + tid;
      int r = c >> 3, kc = (c & 7) * 8;
      gl_lds16(Ah + (size_t)(mtile * 128 + r) * lda + k0 + kc, &As[c * 8]);
      gl_lds16(Bh + (size_t)(ntile * 128 + r) * lda + k0 + kc, &Bs[c * 8]);
      if constexpr (SPLIT) {
        gl_lds16(Al + (size_t)(mtile * 128 + r) * lda + k0 + kc, &As[8192 + c * 8]);
        gl_lds16(Bl + (size_t)(ntile * 128 + r) * lda + k0 + kc, &Bs[8192 + c * 8]);
      }
    }
    __syncthreads();
#pragma unroll
    for (int kk = 0; kk < 2; ++kk) {
      bf16x8 ah[4], bh[4], al[4], bl[4];
#pragma unroll
      for (int i = 0; i < 4; ++i) {
        int ao = (wrow + i * 16 + l15) * 64 + kk * 32 + kg * 8;
        int bo = (wcol + i * 16 + l15) * 64 + kk * 32 + kg * 8;
        ah[i] = *(const bf16x8*)&As[ao];
        bh[i] = *(const bf16x8*)&Bs[bo];
        if constexpr (SPLIT) {
          al[i] = *(const bf16x8*)&As[8192 + ao];
          bl[i] = *(const bf16x8*)&Bs[8192 + bo];
        }
      }
#pragma unroll
      for (int i = 0; i < 4; ++i)
#pragma unroll
        for (int j = 0; j < 4; ++j) {
          f32x4 t = mfma_bf16(ah[i], bh[j], acc[i][j]);
          if constexpr (SPLIT) {
            t = mfma_bf16(ah[i], bl[j], t);
            t = mfma_bf16(al[i], bh[j], t);
          }
          acc[i][j] = t;
        }
    }
    __syncthreads();
  }

  const int r0 = kg * 4;
#pragma unroll
  for (int i = 0; i < 4; ++i) {
    int mbase = mtile * 128 + wrow + i * 16 + r0;
#pragma unroll
    for (int j = 0; j < 4; ++j) {
      int n = ntile * 128 + wcol + j * 16 + l15;
      float bv = bias[n];
#pragma unroll
      for (int reg = 0; reg < 4; ++reg) {
        int m = mbase + reg;
        if (m < Mvalid) {
          float v = acc[i][j][reg] + bv;
          size_t oidx;
          if (REMAP) {
            int b = m & 31, s = m >> 5;
            oidx = ((size_t)(b * TT + s)) * VV + n;
          } else {
            oidx = (size_t)m * out_stride + n;
          }
          out[oidx] = v;
        }
      }
    }
  }
}

// ---------------- recurrence (192 WGs, 64 phases, flag barrier) -------------
// Weights LDS-resident. h-exchange via sc1 atomics in fragment-major layout.
// Per-thread fp32 h_prev in registers.
// L0: WGs 0..63, 16 cols each. LDS rows: [r:0-15][z:16-31][n:32-47].
// L1: WGs 64..191, 8 cols each. LDS rows: [gi_r:0-7][gi_z:8-15][gi_n:16-23]
//     [gh_r:24-31][gh_z:32-39][gh_n:40-47]; B-tiles read rows via l15&7.
// Weight LDS XOR swizzle (both sides): byte ^= (row&7)<<4 within each 2KB row.

struct RecArgs {
  const f16 *wh0, *wi1, *wh1;
  const float *gx0, *bh0, *bi1, *bh1;
  f16 *h0x, *h1x;  // fragment-major exchange buffers, [2][BB*HH] f16
  u16 *hs;
  u32 *bar;  // NWG flag lines, 64B each
};

__global__ __launch_bounds__(256, 1) void rec_kernel(RecArgs ra) {
  __shared__ f16 wlds[48 * 1024];
  __shared__ float gh[48 * 33];
  const int tid = threadIdx.x;
  const int lane = tid & 63, wave = tid >> 6;
  const int wg = blockIdx.x;
  const bool isL0 = wg < 64;
  const int Jbase = isL0 ? (wg * 16) : ((wg - 64) * 8);
  const int l15 = lane & 15;
  const int kg = lane >> 4;
  const int swz = (l15 & 7) << 4;
  char* wb = (char*)wlds;

  // ---- prologue: stage this WG's weight slice into LDS (swizzled) ----
#pragma unroll
  for (int it = 0; it < 24; ++it) {
    int q = it * 256 + tid;  // 0..6143
    int r = q >> 7;          // LDS row 0..47
    int c16 = q & 127;       // 16B chunk within row
    const f16* gp;
    if (isL0) {
      int gate = r >> 4, colr = r & 15;
      gp = ra.wh0 + ((size_t)(gate * HH + Jbase + colr)) * HH + c16 * 8;
    } else {
      int tile = r >> 3, colr = r & 7;
      int msrc = tile / 3, gate = tile - msrc * 3;
      const f16* W = msrc ? ra.wh1 : ra.wi1;
      gp = W + ((size_t)(gate * HH + Jbase + colr)) * HH + c16 * 8;
    }
    f16x8 v = *(const f16x8*)gp;
    int byte = r * 2048 + ((c16 * 16) ^ ((r & 7) << 4));
    *(f16x8*)(wb + byte) = v;
  }

  // ---- per-thread EW state: registers (bias preload, h_prev) ----
  const int ewb = tid & 31, ewjp = tid >> 5;
  float hprev[2] = {0.f, 0.f};
  float pb0r[2], pb0z[2], pb0n[2];                 // L0 biases
  float pbrz_r[2], pbrz_z[2], pbn_i[2], pbn_h[2];  // L1 biases
  if (isL0) {
    const int j0 = ewjp * 2;
#pragma unroll
    for (int s = 0; s < 2; ++s) {
      int gj = Jbase + j0 + s;
      pb0r[s] = ra.bh0[gj];
      pb0z[s] = ra.bh0[HH + gj];
      pb0n[s] = ra.bh0[2 * HH + gj];
    }
  } else if (tid < 128) {
    const int j0 = ewjp * 2;
#pragma unroll
    for (int s = 0; s < 2; ++s) {
      int gj = Jbase + j0 + s;
      pbrz_r[s] = ra.bi1[gj] + ra.bh1[gj];
      pbrz_z[s] = ra.bi1[HH + gj] + ra.bh1[HH + gj];
      pbn_i[s] = ra.bi1[2 * HH + gj];
      pbn_h[s] = ra.bh1[2 * HH + gj];
    }
  }
  __syncthreads();

  for (int p = 0; p < 64; ++p) {
    const int pb = p & 1, qb = (p + 1) & 1;
    if (isL0) {
      if (p < TT) {
        // prefetch gx for this thread's EW (hides HBM latency under MFMA)
        float gr[2], gz[2], gn[2];
        {
          const float* gxb = ra.gx0 + ((size_t)p * BB + ewb) * H3;
          const int j0 = ewjp * 2;
#pragma unroll
          for (int s = 0; s < 2; ++s) {
            int gj = Jbase + j0 + s;
            gr[s] = gxb[gj];
            gz[s] = gxb[HH + gj];
            gn[s] = gxb[2 * HH + gj];
          }
        }
        const int rt = wave >> 1, tt = wave & 1;
        const f16* h0base = ra.h0x + (size_t)qb * (BB * HH);
        const int brow = rt * 16 + l15;
        f32x4 z = {0.f, 0.f, 0.f, 0.f};
        if (tt == 0) {
          f32x4 acc0 = z, acc1 = z;
#pragma unroll 4
          for (int kk = 0; kk < 32; ++kk) {
            f16x8 a = frag_ld(h0base, kk, kg, brow);
            int inner = (kk * 64 + kg * 16) ^ swz;
            f16x8 b0 = *(const f16x8*)(wb + (0 * 16 + l15) * 2048 + inner);
            f16x8 b1 = *(const f16x8*)(wb + (1 * 16 + l15) * 2048 + inner);
            acc0 = mfma_f16(a, b0, acc0);
            acc1 = mfma_f16(a, b1, acc1);
          }
#pragma unroll
          for (int r = 0; r < 4; ++r) {
            gh[(l15)*33 + rt * 16 + kg * 4 + r] = acc0[r];
            gh[(16 + l15) * 33 + rt * 16 + kg * 4 + r] = acc1[r];
          }
        } else {
          f32x4 acc2 = z;
#pragma unroll 4
          for (int kk = 0; kk < 32; ++kk) {
            f16x8 a = frag_ld(h0base, kk, kg, brow);
            int inner = (kk * 64 + kg * 16) ^ swz;
            f16x8 b2 = *(const f16x8*)(wb + (2 * 16 + l15) * 2048 + inner);
            acc2 = mfma_f16(a, b2, acc2);
          }
#pragma unroll
          for (int r = 0; r < 4; ++r)
            gh[(32 + l15) * 33 + rt * 16 + kg * 4 + r] = acc2[r];
        }
        __syncthreads();
        // elementwise
        f16* hxc = ra.h0x + (size_t)pb * (BB * HH);
        const int j0 = ewjp * 2;
        float hn2[2];
#pragma unroll
        for (int s = 0; s < 2; ++s) {
          int j = j0 + s;
          float rh = gh[(j)*33 + ewb] + pb0r[s];
          float zh = gh[(16 + j) * 33 + ewb] + pb0z[s];
          float nh = gh[(32 + j) * 33 + ewb] + pb0n[s];
          float r = sigm(gr[s] + rh);
          float zz = sigm(gz[s] + zh);
          float n = tanh_(gn[s] + r * nh);
          hn2[s] = (1.f - zz) * n + zz * hprev[s];
          hprev[s] = hn2[s];
        }
        union { f16 h[2]; u32 u; } pk;
        pk.h[0] = (f16)hn2[0];
        pk.h[1] = (f16)hn2[1];
        ast32(frag_wslot(hxc, Jbase + j0, ewb), pk.u);
      } else {
        __syncthreads();
      }
    } else {
      if (p >= 1) {
        const int rt = wave >> 1, src = wave & 1;
        const f16* hbase = (src ? ra.h1x : ra.h0x) + (size_t)qb * (BB * HH);
        const int brow = rt * 16 + l15;
        const int rowb = src * 24 + (l15 & 7);
        f32x4 z = {0.f, 0.f, 0.f, 0.f};
        f32x4 acc0 = z, acc1 = z, acc2 = z;
#pragma unroll 4
        for (int kk = 0; kk < 32; ++kk) {
          f16x8 a = frag_ld(hbase, kk, kg, brow);
          int inner = (kk * 64 + kg * 16) ^ swz;
          f16x8 b0 = *(const f16x8*)(wb + (rowb + 0) * 2048 + inner);
          f16x8 b1 = *(const f16x8*)(wb + (rowb + 8) * 2048 + inner);
          f16x8 b2 = *(const f16x8*)(wb + (rowb + 16) * 2048 + inner);
          acc0 = mfma_f16(a, b0, acc0);
          acc1 = mfma_f16(a, b1, acc1);
          acc2 = mfma_f16(a, b2, acc2);
        }
        if (l15 < 8) {
          f32x4 accs[3] = {acc0, acc1, acc2};
#pragma unroll
          for (int g = 0; g < 3; ++g) {
            int cl = (src * 3 + g) * 8 + l15;
#pragma unroll
            for (int r = 0; r < 4; ++r)
              gh[cl * 33 + rt * 16 + kg * 4 + r] = accs[g][r];
          }
        }
        __syncthreads();
        if (tid < 128) {
          f16* hxc = ra.h1x + (size_t)pb * (BB * HH);
          const int j0 = ewjp * 2;
          float hn2[2];
#pragma unroll
          for (int s = 0; s < 2; ++s) {
            int j = j0 + s;
            float gir = gh[(j)*33 + ewb];
            float giz = gh[(8 + j) * 33 + ewb];
            float gin = gh[(16 + j) * 33 + ewb];
            float ghr = gh[(24 + j) * 33 + ewb];
            float ghz = gh[(32 + j) * 33 + ewb];
            float ghn = gh[(40 + j) * 33 + ewb];
            float r = sigm(gir + ghr + pbrz_r[s]);
            float zz = sigm(giz + ghz + pbrz_z[s]);
            float n = tanh_(gin + pbn_i[s] + r * (ghn + pbn_h[s]));
            hn2[s] = (1.f - zz) * n + zz * hprev[s];
            hprev[s] = hn2[s];
          }
          union { f16 h[2]; u32 u; } pk;
          pk.h[0] = (f16)hn2[0];
          pk.h[1] = (f16)hn2[1];
          ast32(frag_wslot(hxc, Jbase + j0, ewb), pk.u);
          union { u16 h[2]; u32 u; } pb2;
          pb2.h[0] = f2bf(hn2[0]);
          pb2.h[1] = f2bf(hn2[1]);
          *(u32*)&ra.hs[((size_t)(p - 1) * BB + ewb) * HH + Jbase + j0] = pb2.u;
        }
      } else {
        __syncthreads();
      }
    }
    if (p < 63) gbar(ra.bar, wg, (u32)(p + 1));
  }
}

// ---------------- row reductions + loss ----------------

__global__ __launch_bounds__(256) void rowred_kernel(const float* __restrict__ logits,
                                                     const int* __restrict__ sent,
                                                     const int* __restrict__ length,
                                                     float* __restrict__ tok) {
  __shared__ float red[8];
  const int row = blockIdx.x;  // b*63 + s
  const int b = row / TT, s = row % TT;
  const float* p = logits + (size_t)row * VV;
  const int tid = threadIdx.x;

  float m = -1e30f;
  for (int i = tid; i < VV; i += 256) m = fmaxf(m, p[i]);
  for (int off = 1; off < 64; off <<= 1) m = fmaxf(m, __shfl_xor(m, off));
  if ((tid & 63) == 0) red[tid >> 6] = m;
  __syncthreads();
  m = fmaxf(fmaxf(red[0], red[1]), fmaxf(red[2], red[3]));

  float sum = 0.f;
  for (int i = tid; i < VV; i += 256) sum += __expf(p[i] - m);
  for (int off = 1; off < 64; off <<= 1) sum += __shfl_xor(sum, off);
  if ((tid & 63) == 0) red[4 + (tid >> 6)] = sum;
  __syncthreads();
  if (tid == 0) {
    float tot = red[4] + red[5] + red[6] + red[7];
    float lse = m + __logf(tot);
    int tgt = sent[b * SS + s + 1];
    float tl = p[tgt] - lse;
    if (s >= length[b] - 1) tl = 0.f;
    tok[row] = tl;
  }
}

__global__ void loss_kernel(const float* __restrict__ tok, const int* __restrict__ length,
                            float* __restrict__ out0) {
  int lane = threadIdx.x;
  float v = 0.f;
  if (lane < BB) {
    float s = 0.f;
    for (int t = 0; t < TT; ++t) s += tok[lane * TT + t];
    float ln = (float)(length[lane] - 1);
    v = -s / ln;
  }
  v += __shfl_down(v, 16);
  v += __shfl_down(v, 8);
  v += __shfl_down(v, 4);
  v += __shfl_down(v, 2);
  v += __shfl_down(v, 1);
  if (lane == 0) out0[0] = v / (float)BB;
}

// ---------------- host ----------------

extern "C" void kernel_launch(void* const* d_in, const int* in_sizes, int n_in,
                              void* d_out, int out_size, void* d_ws, size_t ws_size,
                              hipStream_t stream) {
  const int* sent = (const int*)d_in[0];
  const int* length = (const int*)d_in[1];
  const float* emb = (const float*)d_in[2];
  const float* Wi0 = (const float*)d_in[3];
  const float* Wh0 = (const float*)d_in[4];
  const float* bi0 = (const float*)d_in[5];
  const float* bh0 = (const float*)d_in[6];
  const float* Wi1 = (const float*)d_in[7];
  const float* Wh1 = (const float*)d_in[8];
  const float* bi1 = (const float*)d_in[9];
  const float* bh1 = (const float*)d_in[10];
  const float* Wout = (const float*)d_in[11];
  const float* bout = (const float*)d_in[12];
  float* out = (float*)d_out;

  char* ws = (char*)d_ws;
  // Region A: recurrence-phase-only buffers; woutb aliases it after rec.
  size_t offA = 0;
  auto allocA = [&](size_t b) {
    char* p = ws + offA;
    offA = (offA + b + 255) & ~(size_t)255;
    return p;
  };
  f16* wh0f = (f16*)allocA((size_t)H3 * HH * 2);
  f16* wi1f = (f16*)allocA((size_t)H3 * HH * 2);
  f16* wh1f = (f16*)allocA((size_t)H3 * HH * 2);
  u16* wi0h = (u16*)allocA((size_t)H3 * EP * 2);
  u16* wi0l = (u16*)allocA((size_t)H3 * EP * 2);
  u16* xh = (u16*)allocA((size_t)MP * EP * 2);
  u16* xl = (u16*)allocA((size_t)MP * EP * 2);
  float* gx0 = (float*)allocA((size_t)MM * H3 * 4);
  u16* woutb = (u16*)ws;  // alias over region A, used after rec
  size_t wout_bytes = (size_t)VV * HH * 2;
  size_t off = (offA > wout_bytes ? offA : wout_bytes);
  off = (off + 255) & ~(size_t)255;
  auto alloc = [&](size_t b) {
    char* p = ws + off;
    off = (off + b + 255) & ~(size_t)255;
    return p;
  };

  u16* hs = (u16*)alloc((size_t)MP * HH * 2);
  f16* h0x = (f16*)alloc((size_t)2 * BB * HH * 2);
  f16* h1x = (f16*)alloc((size_t)2 * BB * HH * 2);
  float* tok = (float*)alloc((size_t)MM * 4);
  u32* bar = (u32*)alloc((size_t)NWG * 16 * 4);

  hipMemsetAsync(h0x, 0, (size_t)2 * BB * HH * 2, stream);
  hipMemsetAsync(h1x, 0, (size_t)2 * BB * HH * 2, stream);
  hipMemsetAsync(hs, 0, (size_t)MP * HH * 2, stream);
  hipMemsetAsync(bar, 0, (size_t)NWG * 16 * 4, stream);
  hipMemsetAsync(xh + (size_t)MM * EP, 0, (size_t)(MP - MM) * EP * 2, stream);
  hipMemsetAsync(xl + (size_t)MM * EP, 0, (size_t)(MP - MM) * EP * 2, stream);

  cvt_f16<<<1024, 256, 0, stream>>>(Wh0, wh0f, H3 * HH / 4);
  cvt_f16<<<1024, 256, 0, stream>>>(Wi1, wi1f, H3 * HH / 4);
  cvt_f16<<<1024, 256, 0, stream>>>(Wh1, wh1f, H3 * HH / 4);
  cvt_wi0_split<<<512, 256, 0, stream>>>(Wi0, wi0h, wi0l);
  gather_x_split<<<512, 256, 0, stream>>>(sent, emb, xh, xl);

  gemm_bt<false, true><<<16 * 24, 256, 0, stream>>>(xh, xl, EP, wi0h, wi0l, bi0, gx0, H3,
                                                    5, 16, MM);

  RecArgs ra{wh0f, wi1f, wh1f, gx0, bh0, bi1, bh1, h0x, h1x, hs, bar};
  void* kargs[] = {(void*)&ra};
  hipLaunchCooperativeKernel((void*)rec_kernel, dim3(NWG), dim3(256), kargs, 0, stream);

  // Wout conversion AFTER rec: woutb aliases the (now dead) recurrence weights.
  cvt_bf16<<<2048, 256, 0, stream>>>(Wout, woutb, VV * HH / 4);

  gemm_bt<true, false><<<16 * 250, 256, 0, stream>>>(hs, nullptr, HH, woutb, nullptr, bout,
                                                     out + 1, VV, 16, 16, MM);

  rowred_kernel<<<MM, 256, 0, stream>>>(out + 1, sent, length, tok);
  loss_kernel<<<1, 64, 0, stream>>>(tok, length, out);
}